// Round 2
// baseline (1051.524 us; speedup 1.0000x reference)
//
#include <hip/hip_runtime.h>
#include <cstdint>
#include <cstddef>

#define BB 4
#define NN 100000
#define CC 80
#define NC (NN * CC)          // 8,000,000
#define KTOP 4096
#define PROP 100
#define HBINS 10248           // buckets for (float_bits>>12) - 0x3D000, covers (0.03125, 1.0]
#define BUCKET_BASE 0x3D000u
#define CAPB 16384

// ws layout:
//   [0)                hist   : BB * HBINS * u32   = 163,968 B   (zeroed)
//   [163968)           ctrl   : BB * 8 * u32       = 128 B       (zeroed)  {0:B1, 1:cntAbove, 2:nA, 3:nB}
//   [164096)           candA  : BB * KTOP * u64    = 131,072 B
//   [295168)           candB  : BB * CAPB * u64    = 524,288 B
#define HIST_BYTES (BB * HBINS * 4)
#define CTRL_OFF   HIST_BYTES
#define ZERO_BYTES (HIST_BYTES + 128)
#define CANDA_OFF  (HIST_BYTES + 128)
#define CANDB_OFF  (CANDA_OFF + BB * KTOP * 8)

// ---------------- Pass 1: per-batch histogram of score-key buckets ----------------
__global__ void k_hist(const float* __restrict__ logits, const float* __restrict__ cent,
                       unsigned* __restrict__ hist) {
    int b = blockIdx.y;
    __shared__ unsigned lh[HBINS];
    for (int i = threadIdx.x; i < HBINS; i += blockDim.x) lh[i] = 0;
    __syncthreads();
    const float4* lg = (const float4*)(logits + (size_t)b * NC);
    const float* cb = cent + (size_t)b * NN;
    const int T4 = NC / 4;  // 2,000,000 float4 per batch
    for (int i = blockIdx.x * blockDim.x + threadIdx.x; i < T4; i += gridDim.x * blockDim.x) {
        float4 v = lg[i];
        int n = i / 20;                 // C/4 = 20 float4 per row
        int c4 = (i - n * 20) * 4;
        float ce = cb[n];
        float s;
        s = sqrtf(v.x * ce);
        if (c4 != 0 && s > 0.05f) atomicAdd(&lh[(__float_as_uint(s) >> 12) - BUCKET_BASE], 1u);
        s = sqrtf(v.y * ce);
        if (s > 0.05f) atomicAdd(&lh[(__float_as_uint(s) >> 12) - BUCKET_BASE], 1u);
        s = sqrtf(v.z * ce);
        if (s > 0.05f) atomicAdd(&lh[(__float_as_uint(s) >> 12) - BUCKET_BASE], 1u);
        s = sqrtf(v.w * ce);
        if (s > 0.05f) atomicAdd(&lh[(__float_as_uint(s) >> 12) - BUCKET_BASE], 1u);
    }
    __syncthreads();
    unsigned* gh = hist + (size_t)b * HBINS;
    for (int i = threadIdx.x; i < HBINS; i += blockDim.x) {
        unsigned c = lh[i];
        if (c) atomicAdd(&gh[i], c);
    }
}

// ---------------- Find boundary bucket B1 per batch ----------------
__global__ void k_select(const unsigned* __restrict__ hist, unsigned* __restrict__ ctrl) {
    int b = blockIdx.x;
    int t = threadIdx.x;
    const unsigned* h = hist + (size_t)b * HBINS;
    __shared__ unsigned ssum[256];
    const int CH = (HBINS + 255) / 256;  // 41
    unsigned acc0 = 0;
    for (int i = 0; i < CH; i++) {
        int idx = t * CH + i;
        if (idx < HBINS) acc0 += h[idx];
    }
    ssum[t] = acc0;
    __syncthreads();
    // suffix sums over chunks: ssum[t] = sum_{k>=t} chunk_k
    for (int off = 1; off < 256; off <<= 1) {
        unsigned v = (t + off < 256) ? ssum[t + off] : 0u;
        __syncthreads();
        ssum[t] += v;
        __syncthreads();
    }
    unsigned acc = (t < 255) ? ssum[t + 1] : 0u;  // suffixGE of first bucket AFTER my chunk
    for (int i = CH - 1; i >= 0; i--) {
        int idx = t * CH + i;
        if (idx >= HBINS) continue;
        unsigned cnt = h[idx];
        unsigned na = acc + cnt;  // suffixGE(idx)
        if (na >= KTOP && acc < KTOP) {  // unique crossing bucket
            ctrl[b * 8 + 0] = (unsigned)idx;
            ctrl[b * 8 + 1] = acc;       // count strictly above B1
        }
        acc = na;
    }
    // if total < KTOP: no write happens; ctrl[b*8+0] stays 0 from memset -> all go to candA
}

// ---------------- Pass 2: compact candidates ----------------
__global__ void k_compact(const float* __restrict__ logits, const float* __restrict__ cent,
                          unsigned* __restrict__ ctrl,
                          unsigned long long* __restrict__ candA,
                          unsigned long long* __restrict__ candB) {
    int b = blockIdx.y;
    unsigned B1 = ctrl[b * 8 + 0];
    const float4* lg = (const float4*)(logits + (size_t)b * NC);
    const float* cb = cent + (size_t)b * NN;
    const int T4 = NC / 4;
    unsigned long long* gA = candA + (size_t)b * KTOP;
    unsigned long long* gB = candB + (size_t)b * CAPB;
    for (int i = blockIdx.x * blockDim.x + threadIdx.x; i < T4; i += gridDim.x * blockDim.x) {
        float4 v = lg[i];
        int n = i / 20;
        int c4 = (i - n * 20) * 4;
        float ce = cb[n];
        float sv[4] = {v.x, v.y, v.z, v.w};
#pragma unroll
        for (int k = 0; k < 4; k++) {
            float s = sqrtf(sv[k] * ce);
            int c = c4 + k;
            if (c != 0 && s > 0.05f) {
                unsigned key = __float_as_uint(s);
                unsigned bk = (key >> 12) - BUCKET_BASE;
                if (bk >= B1) {
                    unsigned flat = (unsigned)(i * 4 + k);
                    unsigned long long pk = ((unsigned long long)key << 32) | (unsigned)(~flat);
                    if (bk > B1) {
                        unsigned p = atomicAdd(&ctrl[b * 8 + 2], 1u);
                        if (p < KTOP) gA[p] = pk;
                    } else {
                        unsigned p = atomicAdd(&ctrl[b * 8 + 3], 1u);
                        if (p < CAPB) gB[p] = pk;
                    }
                }
            }
        }
    }
}

// ---------------- Resolve boundary bucket exactly (rank by u64 key desc) ----------------
__global__ void k_boundary(unsigned* __restrict__ ctrl,
                           unsigned long long* __restrict__ candA,
                           const unsigned long long* __restrict__ candB) {
    int b = blockIdx.x;
    int t = threadIdx.x;
    unsigned nA = ctrl[b * 8 + 2];
    if (nA > KTOP) nA = KTOP;
    unsigned nB = ctrl[b * 8 + 3];
    if (nB > CAPB) nB = CAPB;
    int m = (int)KTOP - (int)nA;
    if (m < 0) m = 0;
    __shared__ unsigned long long sB[8192];
    const unsigned long long* gB = candB + (size_t)b * CAPB;
    unsigned long long* gA = candA + (size_t)b * KTOP;
    unsigned nBr = (nB + 255u) & ~255u;
    for (unsigned ii = 0; ii < nBr; ii += 256) {
        unsigned i = ii + (unsigned)t;
        bool act = (i < nB);
        unsigned long long ki = act ? gB[i] : 0ull;
        unsigned rank = 0;
        for (unsigned cb0 = 0; cb0 < nB; cb0 += 8192) {
            unsigned chunk = nB - cb0;
            if (chunk > 8192) chunk = 8192;
            __syncthreads();
            for (unsigned j = (unsigned)t; j < chunk; j += 256) sB[j] = gB[cb0 + j];
            __syncthreads();
            if (act) {
                for (unsigned j = 0; j < chunk; j++) rank += (sB[j] > ki) ? 1u : 0u;
            }
        }
        if (act && rank < (unsigned)m) gA[nA + rank] = ki;
    }
    unsigned take = ((unsigned)m < nB) ? (unsigned)m : nB;
    unsigned filled = nA + take;
    for (unsigned i = filled + (unsigned)t; i < KTOP; i += 256) gA[i] = 0ull;
}

// ---------------- NMS + output ----------------
__global__ void __launch_bounds__(256, 1) k_nms(const float* __restrict__ logits,
                                                const float* __restrict__ regress,
                                                const float* __restrict__ points,
                                                const float* __restrict__ cent,
                                                const unsigned long long* __restrict__ candA,
                                                float* __restrict__ out) {
    int b = blockIdx.x;
    int t = threadIdx.x;
    const unsigned long long* gA = candA + (size_t)b * KTOP;

    unsigned long long key[16];
    float bx1[16], by1[16], bx2[16], by2[16];
    int cls[16];
    unsigned anc[16];
#pragma unroll
    for (int i = 0; i < 16; i++) {
        unsigned long long kk = gA[i * 256 + t];
        key[i] = kk;
        cls[i] = -1;
        anc[i] = 0xFFFFFFFFu;
        bx1[i] = by1[i] = bx2[i] = by2[i] = 0.f;
        if (kk) {
            unsigned idx = ~(unsigned)kk;
            unsigned a = idx / CC;
            unsigned cc = idx - a * CC;
            anc[i] = a;
            cls[i] = (int)cc;
            float px = points[a * 2 + 0], py = points[a * 2 + 1];
            const float* rg = regress + ((size_t)b * NN + a) * 4;
            float l = rg[0], tt = rg[1], r = rg[2], d = rg[3];
            bx1[i] = fminf(fmaxf(px - l, 0.f), 1.f);
            by1[i] = fminf(fmaxf(py - tt, 0.f), 1.f);
            bx2[i] = fminf(fmaxf(px + r, 0.f), 1.f);
            by2[i] = fminf(fmaxf(py + d, 0.f), 1.f);
        }
    }

    __shared__ unsigned long long wkey[4];
    __shared__ float bB[4];
    __shared__ int bC;
    __shared__ unsigned bA;
    __shared__ unsigned selA[PROP];
    __shared__ float selB[PROP][4];
    int lane = t & 63, wid = t >> 6;

    for (int p = 0; p < PROP; p++) {
        // local argmax over 16 (u64 keys are unique except pad zeros)
        unsigned long long lmk = 0;
        int li = -1;
#pragma unroll
        for (int i = 0; i < 16; i++)
            if (key[i] > lmk) { lmk = key[i]; li = i; }
        // wave butterfly max
        unsigned long long rk = lmk;
#pragma unroll
        for (int off = 32; off >= 1; off >>= 1) {
            unsigned long long o = __shfl_xor(rk, off);
            if (o > rk) rk = o;
        }
        if (lane == 0) wkey[wid] = rk;
        __syncthreads();
        unsigned long long bk = wkey[0];
        if (wkey[1] > bk) bk = wkey[1];
        if (wkey[2] > bk) bk = wkey[2];
        if (wkey[3] > bk) bk = wkey[3];
        if (bk && lmk == bk) {  // unique owner
            bB[0] = bx1[li]; bB[1] = by1[li]; bB[2] = bx2[li]; bB[3] = by2[li];
            bC = cls[li];
            bA = anc[li];
            key[li] = 0;
        }
        __syncthreads();
        if (t == 0) {
            if (bk) {
                selA[p] = bA;
                selB[p][0] = bB[0]; selB[p][1] = bB[1]; selB[p][2] = bB[2]; selB[p][3] = bB[3];
            } else {
                selA[p] = 0xFFFFFFFFu;
                selB[p][0] = selB[p][1] = selB[p][2] = selB[p][3] = 0.f;
            }
        }
        if (bk) {
            float jx1 = bB[0], jy1 = bB[1], jx2 = bB[2], jy2 = bB[3];
            int jc = bC;
            float ja = (jx2 - jx1) * (jy2 - jy1);
#pragma unroll
            for (int i = 0; i < 16; i++) {
                if (key[i] && cls[i] == jc) {
                    float ltx = fmaxf(jx1, bx1[i]);
                    float lty = fmaxf(jy1, by1[i]);
                    float rbx = fminf(jx2, bx2[i]);
                    float rby = fminf(jy2, by2[i]);
                    float w = fmaxf(rbx - ltx, 0.f);
                    float h = fmaxf(rby - lty, 0.f);
                    float inter = w * h;
                    float ia = (bx2[i] - bx1[i]) * (by2[i] - by1[i]);
                    float uni = ja + ia - inter;
                    float iou = inter / fmaxf(uni, 1e-9f);
                    if (iou > 0.5f) key[i] = 0;
                }
            }
        }
    }
    __syncthreads();

    // outputs: out_logit [B][PROP][CC] at 0; out_box [B][PROP][4] at B*PROP*CC
    float* outL = out + (size_t)b * PROP * CC;
    const float* lgb = logits + (size_t)b * NC;
    const float* cb = cent + (size_t)b * NN;
    for (int s = t; s < PROP * CC; s += 256) {
        int p = s / CC;
        int c = s - p * CC;
        unsigned a = selA[p];
        float v = 0.f;
        if (a != 0xFFFFFFFFu) v = sqrtf(lgb[(size_t)a * CC + c] * cb[a]);
        outL[s] = v;
    }
    float* outB = out + (size_t)BB * PROP * CC + (size_t)b * PROP * 4;
    for (int s = t; s < PROP * 4; s += 256) {
        outB[s] = selB[s >> 2][s & 3];
    }
}

extern "C" void kernel_launch(void* const* d_in, const int* in_sizes, int n_in,
                              void* d_out, int out_size, void* d_ws, size_t ws_size,
                              hipStream_t stream) {
    const float* logits  = (const float*)d_in[0];
    const float* regress = (const float*)d_in[1];
    const float* points  = (const float*)d_in[2];
    const float* cent    = (const float*)d_in[3];
    float* out = (float*)d_out;

    char* ws = (char*)d_ws;
    unsigned* hist = (unsigned*)ws;
    unsigned* ctrl = (unsigned*)(ws + CTRL_OFF);
    unsigned long long* candA = (unsigned long long*)(ws + CANDA_OFF);
    unsigned long long* candB = (unsigned long long*)(ws + CANDB_OFF);

    hipMemsetAsync(d_ws, 0, ZERO_BYTES, stream);
    k_hist<<<dim3(256, BB), 256, 0, stream>>>(logits, cent, hist);
    k_select<<<BB, 256, 0, stream>>>(hist, ctrl);
    k_compact<<<dim3(256, BB), 256, 0, stream>>>(logits, cent, ctrl, candA, candB);
    k_boundary<<<BB, 256, 0, stream>>>(ctrl, candA, candB);
    k_nms<<<BB, 256, 0, stream>>>(logits, regress, points, cent, candA, out);
}

// Round 3
// 1022.713 us; speedup vs baseline: 1.0282x; 1.0282x over previous
//
#include <hip/hip_runtime.h>
#include <cstdint>
#include <cstddef>

#define BB 4
#define NN 100000
#define CC 80
#define NC (NN * CC)          // 8,000,000
#define KTOP 4096
#define PROP 100
#define HBINS 10248           // buckets for (float_bits>>12) - 0x3D000, covers (0.03125, 1.0]
#define BUCKET_BASE 0x3D000u
#define CAPB 16384
#define SPILLCAP 131072
#define T0BK 0x3F733u         // absolute bucket threshold: s >= 0.94989...
#define SPILL_LO (T0BK - BUCKET_BASE)     // 10035
#define SPILL_BINS (HBINS - SPILL_LO)     // 213

// ws layout:
//   [0)        hist  : BB * HBINS * u32 = 163,968 B (zeroed)
//   [163968)   ctrl  : 128 B (zeroed)  per-batch b*8+{0:B1, 1:cntAbove, 2:nA, 3:nB, 4:nSpill}; ctrl[7]=needFull flag
//   [164096)   candA : BB * KTOP * u64 = 131,072 B
//   [295168)   candB : BB * CAPB * u64 = 524,288 B
//   [819456)   spill : BB * SPILLCAP * u64 = 4,194,304 B
#define HIST_BYTES (BB * HBINS * 4)
#define CTRL_OFF   HIST_BYTES
#define ZERO_BYTES (HIST_BYTES + 128)
#define CANDA_OFF  (HIST_BYTES + 128)
#define CANDB_OFF  (CANDA_OFF + BB * KTOP * 8)
#define SPILL_OFF  (CANDB_OFF + BB * CAPB * 8)
#define WS_NEEDED  ((size_t)SPILL_OFF + (size_t)BB * SPILLCAP * 8)

__device__ __forceinline__ void agg_push(bool pred, unsigned long long pk,
                                         unsigned* counter, unsigned long long* buf,
                                         unsigned cap, int lane) {
    unsigned long long m = __ballot(pred);
    if (m) {
        int leader = __ffsll(m) - 1;
        unsigned base = 0;
        if (lane == leader) base = atomicAdd(counter, (unsigned)__popcll(m));
        base = (unsigned)__shfl((int)base, leader);
        if (pred) {
            unsigned pos = base + (unsigned)__popcll(m & ((1ull << lane) - 1ull));
            if (pos < cap) buf[pos] = pk;
        }
    }
}

// ---------------- FAST pass 1: filter s>=bucket(T0BK), spill packed keys ----------------
__global__ void k_pass1(const float* __restrict__ logits, const float* __restrict__ cent,
                        unsigned* __restrict__ ctrl, unsigned long long* __restrict__ spill) {
    int b = blockIdx.y;
    const float4* lg = (const float4*)(logits + (size_t)b * NC);
    const float* cb = cent + (size_t)b * NN;
    unsigned long long* sp = spill + (size_t)b * SPILLCAP;
    unsigned* nsp = &ctrl[b * 8 + 4];
    const int T4 = NC / 4;
    int lane = threadIdx.x & 63;
    for (int i = blockIdx.x * blockDim.x + threadIdx.x; i < T4; i += gridDim.x * blockDim.x) {
        float4 v = lg[i];
        int n = i / 20;
        int c4 = (i - n * 20) * 4;
        float ce = cb[n];
        float s0 = sqrtf(v.x * ce), s1 = sqrtf(v.y * ce), s2 = sqrtf(v.z * ce), s3 = sqrtf(v.w * ce);
        unsigned k0 = __float_as_uint(s0), k1 = __float_as_uint(s1);
        unsigned k2 = __float_as_uint(s2), k3 = __float_as_uint(s3);
        bool p0 = (c4 != 0) && ((k0 >> 12) >= T0BK);
        bool p1 = (k1 >> 12) >= T0BK;
        bool p2 = (k2 >> 12) >= T0BK;
        bool p3 = (k3 >> 12) >= T0BK;
        if (__any(p0 | p1 | p2 | p3)) {
            unsigned f = (unsigned)i * 4u;
            agg_push(p0, ((unsigned long long)k0 << 32) | (unsigned)(~(f + 0)), nsp, sp, SPILLCAP, lane);
            agg_push(p1, ((unsigned long long)k1 << 32) | (unsigned)(~(f + 1)), nsp, sp, SPILLCAP, lane);
            agg_push(p2, ((unsigned long long)k2 << 32) | (unsigned)(~(f + 2)), nsp, sp, SPILLCAP, lane);
            agg_push(p3, ((unsigned long long)k3 << 32) | (unsigned)(~(f + 3)), nsp, sp, SPILLCAP, lane);
        }
    }
}

// ---------------- decide fast/slow path ----------------
__global__ void k_slowflag(unsigned* __restrict__ ctrl) {
    if (threadIdx.x == 0 && blockIdx.x == 0) {
        unsigned f = 0;
        for (int b = 0; b < BB; b++) {
            unsigned ns = ctrl[b * 8 + 4];
            if (ns < KTOP || ns > SPILLCAP) f = 1;
        }
        ctrl[7] = f;
    }
}

// ---------------- FAST: histogram the spill buffer ----------------
__global__ void k_hist_spill(const unsigned* __restrict__ ctrl,
                             const unsigned long long* __restrict__ spill,
                             unsigned* __restrict__ hist) {
    if (ctrl[7]) return;
    int b = blockIdx.y;
    __shared__ unsigned lh[SPILL_BINS];
    for (int i = threadIdx.x; i < SPILL_BINS; i += blockDim.x) lh[i] = 0;
    __syncthreads();
    unsigned ns = ctrl[b * 8 + 4];
    if (ns > SPILLCAP) ns = SPILLCAP;
    const unsigned long long* sp = spill + (size_t)b * SPILLCAP;
    for (unsigned i = blockIdx.x * blockDim.x + threadIdx.x; i < ns; i += gridDim.x * blockDim.x) {
        unsigned bits = (unsigned)(sp[i] >> 32);
        atomicAdd(&lh[(bits >> 12) - T0BK], 1u);
    }
    __syncthreads();
    unsigned* gh = hist + (size_t)b * HBINS + SPILL_LO;
    for (int i = threadIdx.x; i < SPILL_BINS; i += blockDim.x) {
        unsigned c = lh[i];
        if (c) atomicAdd(&gh[i], c);
    }
}

// ---------------- SLOW (guarded) full histogram — validated round-2 path ----------------
__global__ void k_hist(const float* __restrict__ logits, const float* __restrict__ cent,
                       unsigned* __restrict__ hist, const unsigned* __restrict__ ctrl) {
    if (ctrl[7] == 0) return;
    int b = blockIdx.y;
    __shared__ unsigned lh[HBINS];
    for (int i = threadIdx.x; i < HBINS; i += blockDim.x) lh[i] = 0;
    __syncthreads();
    const float4* lg = (const float4*)(logits + (size_t)b * NC);
    const float* cb = cent + (size_t)b * NN;
    const int T4 = NC / 4;
    for (int i = blockIdx.x * blockDim.x + threadIdx.x; i < T4; i += gridDim.x * blockDim.x) {
        float4 v = lg[i];
        int n = i / 20;
        int c4 = (i - n * 20) * 4;
        float ce = cb[n];
        float s;
        s = sqrtf(v.x * ce);
        if (c4 != 0 && s > 0.05f) atomicAdd(&lh[(__float_as_uint(s) >> 12) - BUCKET_BASE], 1u);
        s = sqrtf(v.y * ce);
        if (s > 0.05f) atomicAdd(&lh[(__float_as_uint(s) >> 12) - BUCKET_BASE], 1u);
        s = sqrtf(v.z * ce);
        if (s > 0.05f) atomicAdd(&lh[(__float_as_uint(s) >> 12) - BUCKET_BASE], 1u);
        s = sqrtf(v.w * ce);
        if (s > 0.05f) atomicAdd(&lh[(__float_as_uint(s) >> 12) - BUCKET_BASE], 1u);
    }
    __syncthreads();
    unsigned* gh = hist + (size_t)b * HBINS;
    for (int i = threadIdx.x; i < HBINS; i += blockDim.x) {
        unsigned c = lh[i];
        if (c) atomicAdd(&gh[i], c);
    }
}

// ---------------- Find boundary bucket B1 per batch (path-agnostic) ----------------
__global__ void k_select(const unsigned* __restrict__ hist, unsigned* __restrict__ ctrl) {
    int b = blockIdx.x;
    int t = threadIdx.x;
    const unsigned* h = hist + (size_t)b * HBINS;
    __shared__ unsigned ssum[256];
    const int CH = (HBINS + 255) / 256;  // 41
    unsigned acc0 = 0;
    for (int i = 0; i < CH; i++) {
        int idx = t * CH + i;
        if (idx < HBINS) acc0 += h[idx];
    }
    ssum[t] = acc0;
    __syncthreads();
    for (int off = 1; off < 256; off <<= 1) {
        unsigned v = (t + off < 256) ? ssum[t + off] : 0u;
        __syncthreads();
        ssum[t] += v;
        __syncthreads();
    }
    unsigned acc = (t < 255) ? ssum[t + 1] : 0u;
    for (int i = CH - 1; i >= 0; i--) {
        int idx = t * CH + i;
        if (idx >= HBINS) continue;
        unsigned cnt = h[idx];
        unsigned na = acc + cnt;
        if (na >= KTOP && acc < KTOP) {
            ctrl[b * 8 + 0] = (unsigned)idx;
            ctrl[b * 8 + 1] = acc;
        }
        acc = na;
    }
}

// ---------------- FAST: partition spill by B1 ----------------
__global__ void k_compact_fast(unsigned* __restrict__ ctrl,
                               const unsigned long long* __restrict__ spill,
                               unsigned long long* __restrict__ candA,
                               unsigned long long* __restrict__ candB) {
    if (ctrl[7]) return;
    int b = blockIdx.y;
    unsigned B1 = ctrl[b * 8 + 0];
    unsigned ns = ctrl[b * 8 + 4];
    if (ns > SPILLCAP) ns = SPILLCAP;
    const unsigned long long* sp = spill + (size_t)b * SPILLCAP;
    unsigned long long* gA = candA + (size_t)b * KTOP;
    unsigned long long* gB = candB + (size_t)b * CAPB;
    int lane = threadIdx.x & 63;
    unsigned TT = gridDim.x * blockDim.x;
    unsigned iters = (ns + TT - 1) / TT;
    for (unsigned k2 = 0; k2 < iters; k2++) {
        unsigned i = k2 * TT + blockIdx.x * blockDim.x + threadIdx.x;
        bool active = (i < ns);
        unsigned long long pk = active ? sp[i] : 0ull;
        unsigned bk = active ? (((unsigned)(pk >> 32)) >> 12) - BUCKET_BASE : 0u;
        bool pA = active && (bk > B1);
        bool pB = active && (bk == B1);
        agg_push(pA, pk, &ctrl[b * 8 + 2], gA, KTOP, lane);
        agg_push(pB, pk, &ctrl[b * 8 + 3], gB, CAPB, lane);
    }
}

// ---------------- SLOW (guarded) full compact — validated round-2 path ----------------
__global__ void k_compact(const float* __restrict__ logits, const float* __restrict__ cent,
                          unsigned* __restrict__ ctrl,
                          unsigned long long* __restrict__ candA,
                          unsigned long long* __restrict__ candB) {
    if (ctrl[7] == 0) return;
    int b = blockIdx.y;
    unsigned B1 = ctrl[b * 8 + 0];
    const float4* lg = (const float4*)(logits + (size_t)b * NC);
    const float* cb = cent + (size_t)b * NN;
    const int T4 = NC / 4;
    unsigned long long* gA = candA + (size_t)b * KTOP;
    unsigned long long* gB = candB + (size_t)b * CAPB;
    for (int i = blockIdx.x * blockDim.x + threadIdx.x; i < T4; i += gridDim.x * blockDim.x) {
        float4 v = lg[i];
        int n = i / 20;
        int c4 = (i - n * 20) * 4;
        float ce = cb[n];
        float sv[4] = {v.x, v.y, v.z, v.w};
#pragma unroll
        for (int k = 0; k < 4; k++) {
            float s = sqrtf(sv[k] * ce);
            int c = c4 + k;
            if (c != 0 && s > 0.05f) {
                unsigned key = __float_as_uint(s);
                unsigned bk = (key >> 12) - BUCKET_BASE;
                if (bk >= B1) {
                    unsigned flat = (unsigned)(i * 4 + k);
                    unsigned long long pk = ((unsigned long long)key << 32) | (unsigned)(~flat);
                    if (bk > B1) {
                        unsigned p = atomicAdd(&ctrl[b * 8 + 2], 1u);
                        if (p < KTOP) gA[p] = pk;
                    } else {
                        unsigned p = atomicAdd(&ctrl[b * 8 + 3], 1u);
                        if (p < CAPB) gB[p] = pk;
                    }
                }
            }
        }
    }
}

// ---------------- Resolve boundary bucket exactly ----------------
__global__ void k_boundary(unsigned* __restrict__ ctrl,
                           unsigned long long* __restrict__ candA,
                           const unsigned long long* __restrict__ candB) {
    int b = blockIdx.x;
    int t = threadIdx.x;
    unsigned nA = ctrl[b * 8 + 2];
    if (nA > KTOP) nA = KTOP;
    unsigned nB = ctrl[b * 8 + 3];
    if (nB > CAPB) nB = CAPB;
    int m = (int)KTOP - (int)nA;
    if (m < 0) m = 0;
    __shared__ unsigned long long sB[8192];
    const unsigned long long* gB = candB + (size_t)b * CAPB;
    unsigned long long* gA = candA + (size_t)b * KTOP;
    unsigned nBr = (nB + 255u) & ~255u;
    for (unsigned ii = 0; ii < nBr; ii += 256) {
        unsigned i = ii + (unsigned)t;
        bool act = (i < nB);
        unsigned long long ki = act ? gB[i] : 0ull;
        unsigned rank = 0;
        for (unsigned cb0 = 0; cb0 < nB; cb0 += 8192) {
            unsigned chunk = nB - cb0;
            if (chunk > 8192) chunk = 8192;
            __syncthreads();
            for (unsigned j = (unsigned)t; j < chunk; j += 256) sB[j] = gB[cb0 + j];
            __syncthreads();
            if (act) {
                for (unsigned j = 0; j < chunk; j++) rank += (sB[j] > ki) ? 1u : 0u;
            }
        }
        if (act && rank < (unsigned)m) gA[nA + rank] = ki;
    }
    unsigned take = ((unsigned)m < nB) ? (unsigned)m : nB;
    unsigned filled = nA + take;
    for (unsigned i = filled + (unsigned)t; i < KTOP; i += 256) gA[i] = 0ull;
}

// ---------------- NMS + output (all candidate state static-indexed -> registers) ----------------
__global__ void __launch_bounds__(256, 1) k_nms(const float* __restrict__ logits,
                                                const float* __restrict__ regress,
                                                const float* __restrict__ points,
                                                const float* __restrict__ cent,
                                                const unsigned long long* __restrict__ candA,
                                                float* __restrict__ out) {
    int b = blockIdx.x;
    int t = threadIdx.x;
    const unsigned long long* gA = candA + (size_t)b * KTOP;

    unsigned long long key[16];
    float bx1[16], by1[16], bx2[16], by2[16], ar[16];
    int cls[16];
    unsigned anc[16];
#pragma unroll
    for (int i = 0; i < 16; i++) {
        unsigned long long kk = gA[i * 256 + t];
        key[i] = kk;
        cls[i] = -1;
        anc[i] = 0xFFFFFFFFu;
        bx1[i] = by1[i] = bx2[i] = by2[i] = ar[i] = 0.f;
        if (kk) {
            unsigned idx = ~(unsigned)kk;
            unsigned a = idx / CC;
            unsigned cc = idx - a * CC;
            anc[i] = a;
            cls[i] = (int)cc;
            float px = points[a * 2 + 0], py = points[a * 2 + 1];
            const float* rg = regress + ((size_t)b * NN + a) * 4;
            float x1 = fminf(fmaxf(px - rg[0], 0.f), 1.f);
            float y1 = fminf(fmaxf(py - rg[1], 0.f), 1.f);
            float x2 = fminf(fmaxf(px + rg[2], 0.f), 1.f);
            float y2 = fminf(fmaxf(py + rg[3], 0.f), 1.f);
            bx1[i] = x1; by1[i] = y1; bx2[i] = x2; by2[i] = y2;
            ar[i] = (x2 - x1) * (y2 - y1);
        }
    }

    __shared__ unsigned long long wkey[4];
    __shared__ float sb[5];   // winner x1,y1,x2,y2,area
    __shared__ int sc;
    __shared__ unsigned sa;
    __shared__ unsigned selA[PROP];
    __shared__ float selB[PROP][4];
    int lane = t & 63, wid = t >> 6;

    for (int p = 0; p < PROP; p++) {
        unsigned long long lmk = 0;
#pragma unroll
        for (int i = 0; i < 16; i++) lmk = key[i] > lmk ? key[i] : lmk;
        unsigned long long rk = lmk;
#pragma unroll
        for (int off = 32; off >= 1; off >>= 1) {
            unsigned long long o = __shfl_xor(rk, off);
            rk = o > rk ? o : rk;
        }
        if (lane == 0) wkey[wid] = rk;
        __syncthreads();
        unsigned long long bk = wkey[0];
        bk = wkey[1] > bk ? wkey[1] : bk;
        bk = wkey[2] > bk ? wkey[2] : bk;
        bk = wkey[3] > bk ? wkey[3] : bk;
        if (bk) {
            // winner extraction with STATIC indices only (keys unique, exactly one match)
#pragma unroll
            for (int i = 0; i < 16; i++) {
                if (key[i] == bk) {
                    sb[0] = bx1[i]; sb[1] = by1[i]; sb[2] = bx2[i]; sb[3] = by2[i]; sb[4] = ar[i];
                    sc = cls[i]; sa = anc[i];
                    key[i] = 0;
                }
            }
        }
        __syncthreads();
        if (t == 0) {
            if (bk) {
                selA[p] = sa;
                selB[p][0] = sb[0]; selB[p][1] = sb[1]; selB[p][2] = sb[2]; selB[p][3] = sb[3];
            } else {
                selA[p] = 0xFFFFFFFFu;
                selB[p][0] = selB[p][1] = selB[p][2] = selB[p][3] = 0.f;
            }
        }
        if (bk) {
            float jx1 = sb[0], jy1 = sb[1], jx2 = sb[2], jy2 = sb[3], ja = sb[4];
            int jc = sc;
#pragma unroll
            for (int i = 0; i < 16; i++) {
                if (cls[i] == jc) {
                    float w = fmaxf(fminf(jx2, bx2[i]) - fmaxf(jx1, bx1[i]), 0.f);
                    float h = fmaxf(fminf(jy2, by2[i]) - fmaxf(jy1, by1[i]), 0.f);
                    float inter = w * h;
                    float uni = ja + ar[i] - inter;
                    float iou = inter / fmaxf(uni, 1e-9f);
                    if (iou > 0.5f) key[i] = 0;
                }
            }
        }
    }
    __syncthreads();

    float* outL = out + (size_t)b * PROP * CC;
    const float* lgb = logits + (size_t)b * NC;
    const float* cb = cent + (size_t)b * NN;
    for (int s = t; s < PROP * CC; s += 256) {
        int p = s / CC;
        int c = s - p * CC;
        unsigned a = selA[p];
        float v = 0.f;
        if (a != 0xFFFFFFFFu) v = sqrtf(lgb[(size_t)a * CC + c] * cb[a]);
        outL[s] = v;
    }
    float* outB = out + (size_t)BB * PROP * CC + (size_t)b * PROP * 4;
    for (int s = t; s < PROP * 4; s += 256) {
        outB[s] = selB[s >> 2][s & 3];
    }
}

extern "C" void kernel_launch(void* const* d_in, const int* in_sizes, int n_in,
                              void* d_out, int out_size, void* d_ws, size_t ws_size,
                              hipStream_t stream) {
    const float* logits  = (const float*)d_in[0];
    const float* regress = (const float*)d_in[1];
    const float* points  = (const float*)d_in[2];
    const float* cent    = (const float*)d_in[3];
    float* out = (float*)d_out;

    char* ws = (char*)d_ws;
    unsigned* hist = (unsigned*)ws;
    unsigned* ctrl = (unsigned*)(ws + CTRL_OFF);
    unsigned long long* candA = (unsigned long long*)(ws + CANDA_OFF);
    unsigned long long* candB = (unsigned long long*)(ws + CANDB_OFF);
    unsigned long long* spill = (unsigned long long*)(ws + SPILL_OFF);

    hipMemsetAsync(d_ws, 0, ZERO_BYTES, stream);
    if (ws_size >= WS_NEEDED) {
        k_pass1<<<dim3(512, BB), 256, 0, stream>>>(logits, cent, ctrl, spill);
        k_slowflag<<<1, 64, 0, stream>>>(ctrl);
        k_hist_spill<<<dim3(32, BB), 256, 0, stream>>>(ctrl, spill, hist);
        k_hist<<<dim3(256, BB), 256, 0, stream>>>(logits, cent, hist, ctrl);        // guarded slow path
        k_select<<<BB, 256, 0, stream>>>(hist, ctrl);
        k_compact_fast<<<dim3(32, BB), 256, 0, stream>>>(ctrl, spill, candA, candB);
        k_compact<<<dim3(256, BB), 256, 0, stream>>>(logits, cent, ctrl, candA, candB);  // guarded slow path
    } else {
        // ws too small for spill buffer: force validated full-scan path (ctrl[7]=1)
        hipMemsetAsync(ws + CTRL_OFF + 28, 1, 1, stream);
        k_hist<<<dim3(256, BB), 256, 0, stream>>>(logits, cent, hist, ctrl);
        k_select<<<BB, 256, 0, stream>>>(hist, ctrl);
        k_compact<<<dim3(256, BB), 256, 0, stream>>>(logits, cent, ctrl, candA, candB);
    }
    k_boundary<<<BB, 256, 0, stream>>>(ctrl, candA, candB);
    k_nms<<<BB, 256, 0, stream>>>(logits, regress, points, cent, candA, out);
}

// Round 4
// 523.196 us; speedup vs baseline: 2.0098x; 1.9547x over previous
//
#include <hip/hip_runtime.h>
#include <cstdint>
#include <cstddef>

#define BB 4
#define NN 100000
#define CC 80
#define NC (NN * CC)          // 8,000,000
#define KTOP 4096
#define PROP 100
#define HBINS 10248           // buckets for (float_bits>>12) - 0x3D000, covers (0.03125, 1.0]
#define BUCKET_BASE 0x3D000u
#define CAPB 16384
#define SPILLCAP 131072
#define T0BK 0x3F733u         // absolute bucket threshold: s >= 0.94989...
#define SPILL_LO (T0BK - BUCKET_BASE)     // 10035
#define SPILL_BINS (HBINS - SPILL_LO)     // 213
#define P1CAP 1024            // per-block LDS spill buffer entries

// ws layout:
//   [0)        hist  : BB * HBINS * u32 = 163,968 B (zeroed)
//   [163968)   ctrl  : 128 B (zeroed)  b*8+{0:B1,1:cntAbove,2:nA,3:nB,4:nSpill}; ctrl[6]=p1 overflow, ctrl[7]=needFull
//   [164096)   candA : BB * KTOP * u64
//   [295168)   candB : BB * CAPB * u64
//   [819456)   spill : BB * SPILLCAP * u64
#define HIST_BYTES (BB * HBINS * 4)
#define CTRL_OFF   HIST_BYTES
#define ZERO_BYTES (HIST_BYTES + 128)
#define CANDA_OFF  (HIST_BYTES + 128)
#define CANDB_OFF  (CANDA_OFF + BB * KTOP * 8)
#define SPILL_OFF  (CANDB_OFF + BB * CAPB * 8)
#define WS_NEEDED  ((size_t)SPILL_OFF + (size_t)BB * SPILLCAP * 8)

__device__ __forceinline__ void agg_push(bool pred, unsigned long long pk,
                                         unsigned* counter, unsigned long long* buf,
                                         unsigned cap, int lane) {
    unsigned long long m = __ballot(pred);
    if (m) {
        int leader = __ffsll(m) - 1;
        unsigned base = 0;
        if (lane == leader) base = atomicAdd(counter, (unsigned)__popcll(m));
        base = (unsigned)__shfl((int)base, leader);
        if (pred) {
            unsigned pos = base + (unsigned)__popcll(m & ((1ull << lane) - 1ull));
            if (pos < cap) buf[pos] = pk;
        }
    }
}

// ---------------- FAST pass 1: filter s>=bucket(T0BK); LDS-staged spill ----------------
__global__ void k_pass1(const float* __restrict__ logits, const float* __restrict__ cent,
                        unsigned* __restrict__ ctrl, unsigned long long* __restrict__ spill) {
    int b = blockIdx.y;
    __shared__ unsigned long long lbuf[P1CAP];
    __shared__ unsigned lcnt, gbase, lflush;
    if (threadIdx.x == 0) lcnt = 0;
    __syncthreads();
    const float4* lg = (const float4*)(logits + (size_t)b * NC);
    const float* cb = cent + (size_t)b * NN;
    const int T4 = NC / 4;
    for (int i = blockIdx.x * blockDim.x + threadIdx.x; i < T4; i += gridDim.x * blockDim.x) {
        float4 v = lg[i];
        int n = i / 20;
        int c4 = (i - n * 20) * 4;
        float ce = cb[n];
        unsigned k0 = __float_as_uint(sqrtf(v.x * ce));
        unsigned k1 = __float_as_uint(sqrtf(v.y * ce));
        unsigned k2 = __float_as_uint(sqrtf(v.z * ce));
        unsigned k3 = __float_as_uint(sqrtf(v.w * ce));
        bool p0 = (c4 != 0) && ((k0 >> 12) >= T0BK);
        bool p1 = (k1 >> 12) >= T0BK;
        bool p2 = (k2 >> 12) >= T0BK;
        bool p3 = (k3 >> 12) >= T0BK;
        if (p0 | p1 | p2 | p3) {
            unsigned f = (unsigned)i * 4u;
            if (p0) { unsigned q = atomicAdd(&lcnt, 1u); if (q < P1CAP) lbuf[q] = ((unsigned long long)k0 << 32) | (unsigned)(~(f + 0)); }
            if (p1) { unsigned q = atomicAdd(&lcnt, 1u); if (q < P1CAP) lbuf[q] = ((unsigned long long)k1 << 32) | (unsigned)(~(f + 1)); }
            if (p2) { unsigned q = atomicAdd(&lcnt, 1u); if (q < P1CAP) lbuf[q] = ((unsigned long long)k2 << 32) | (unsigned)(~(f + 2)); }
            if (p3) { unsigned q = atomicAdd(&lcnt, 1u); if (q < P1CAP) lbuf[q] = ((unsigned long long)k3 << 32) | (unsigned)(~(f + 3)); }
        }
    }
    __syncthreads();
    if (threadIdx.x == 0) {
        unsigned n = lcnt;
        if (n > P1CAP) { atomicOr(&ctrl[6], 1u); n = P1CAP; }
        lflush = n;
        gbase = n ? atomicAdd(&ctrl[b * 8 + 4], n) : 0u;
    }
    __syncthreads();
    unsigned long long* sp = spill + (size_t)b * SPILLCAP;
    unsigned n = lflush, g0 = gbase;
    for (unsigned i = threadIdx.x; i < n; i += blockDim.x) {
        unsigned pos = g0 + i;
        if (pos < SPILLCAP) sp[pos] = lbuf[i];
    }
}

// ---------------- decide fast/slow path ----------------
__global__ void k_slowflag(unsigned* __restrict__ ctrl) {
    if (threadIdx.x == 0 && blockIdx.x == 0) {
        unsigned f = ctrl[6] ? 1u : 0u;
        for (int b = 0; b < BB; b++) {
            unsigned ns = ctrl[b * 8 + 4];
            if (ns < KTOP || ns > SPILLCAP) f = 1;
        }
        ctrl[7] = f;
    }
}

// ---------------- FAST: histogram the spill buffer ----------------
__global__ void k_hist_spill(const unsigned* __restrict__ ctrl,
                             const unsigned long long* __restrict__ spill,
                             unsigned* __restrict__ hist) {
    if (ctrl[7]) return;
    int b = blockIdx.y;
    __shared__ unsigned lh[SPILL_BINS];
    for (int i = threadIdx.x; i < SPILL_BINS; i += blockDim.x) lh[i] = 0;
    __syncthreads();
    unsigned ns = ctrl[b * 8 + 4];
    if (ns > SPILLCAP) ns = SPILLCAP;
    const unsigned long long* sp = spill + (size_t)b * SPILLCAP;
    for (unsigned i = blockIdx.x * blockDim.x + threadIdx.x; i < ns; i += gridDim.x * blockDim.x) {
        unsigned bits = (unsigned)(sp[i] >> 32);
        atomicAdd(&lh[(bits >> 12) - T0BK], 1u);
    }
    __syncthreads();
    unsigned* gh = hist + (size_t)b * HBINS + SPILL_LO;
    for (int i = threadIdx.x; i < SPILL_BINS; i += blockDim.x) {
        unsigned c = lh[i];
        if (c) atomicAdd(&gh[i], c);
    }
}

// ---------------- SLOW (guarded) full histogram ----------------
__global__ void k_hist(const float* __restrict__ logits, const float* __restrict__ cent,
                       unsigned* __restrict__ hist, const unsigned* __restrict__ ctrl) {
    if (ctrl[7] == 0) return;
    int b = blockIdx.y;
    __shared__ unsigned lh[HBINS];
    for (int i = threadIdx.x; i < HBINS; i += blockDim.x) lh[i] = 0;
    __syncthreads();
    const float4* lg = (const float4*)(logits + (size_t)b * NC);
    const float* cb = cent + (size_t)b * NN;
    const int T4 = NC / 4;
    for (int i = blockIdx.x * blockDim.x + threadIdx.x; i < T4; i += gridDim.x * blockDim.x) {
        float4 v = lg[i];
        int n = i / 20;
        int c4 = (i - n * 20) * 4;
        float ce = cb[n];
        float s;
        s = sqrtf(v.x * ce);
        if (c4 != 0 && s > 0.05f) atomicAdd(&lh[(__float_as_uint(s) >> 12) - BUCKET_BASE], 1u);
        s = sqrtf(v.y * ce);
        if (s > 0.05f) atomicAdd(&lh[(__float_as_uint(s) >> 12) - BUCKET_BASE], 1u);
        s = sqrtf(v.z * ce);
        if (s > 0.05f) atomicAdd(&lh[(__float_as_uint(s) >> 12) - BUCKET_BASE], 1u);
        s = sqrtf(v.w * ce);
        if (s > 0.05f) atomicAdd(&lh[(__float_as_uint(s) >> 12) - BUCKET_BASE], 1u);
    }
    __syncthreads();
    unsigned* gh = hist + (size_t)b * HBINS;
    for (int i = threadIdx.x; i < HBINS; i += blockDim.x) {
        unsigned c = lh[i];
        if (c) atomicAdd(&gh[i], c);
    }
}

// ---------------- Find boundary bucket B1 per batch ----------------
__global__ void k_select(const unsigned* __restrict__ hist, unsigned* __restrict__ ctrl) {
    int b = blockIdx.x;
    int t = threadIdx.x;
    const unsigned* h = hist + (size_t)b * HBINS;
    __shared__ unsigned ssum[256];
    const int CH = (HBINS + 255) / 256;  // 41
    unsigned acc0 = 0;
    for (int i = 0; i < CH; i++) {
        int idx = t * CH + i;
        if (idx < HBINS) acc0 += h[idx];
    }
    ssum[t] = acc0;
    __syncthreads();
    for (int off = 1; off < 256; off <<= 1) {
        unsigned v = (t + off < 256) ? ssum[t + off] : 0u;
        __syncthreads();
        ssum[t] += v;
        __syncthreads();
    }
    unsigned acc = (t < 255) ? ssum[t + 1] : 0u;
    for (int i = CH - 1; i >= 0; i--) {
        int idx = t * CH + i;
        if (idx >= HBINS) continue;
        unsigned cnt = h[idx];
        unsigned na = acc + cnt;
        if (na >= KTOP && acc < KTOP) {
            ctrl[b * 8 + 0] = (unsigned)idx;
            ctrl[b * 8 + 1] = acc;
        }
        acc = na;
    }
}

// ---------------- FAST: partition spill by B1 ----------------
__global__ void k_compact_fast(unsigned* __restrict__ ctrl,
                               const unsigned long long* __restrict__ spill,
                               unsigned long long* __restrict__ candA,
                               unsigned long long* __restrict__ candB) {
    if (ctrl[7]) return;
    int b = blockIdx.y;
    unsigned B1 = ctrl[b * 8 + 0];
    unsigned ns = ctrl[b * 8 + 4];
    if (ns > SPILLCAP) ns = SPILLCAP;
    const unsigned long long* sp = spill + (size_t)b * SPILLCAP;
    unsigned long long* gA = candA + (size_t)b * KTOP;
    unsigned long long* gB = candB + (size_t)b * CAPB;
    int lane = threadIdx.x & 63;
    unsigned TT = gridDim.x * blockDim.x;
    unsigned iters = (ns + TT - 1) / TT;
    for (unsigned k2 = 0; k2 < iters; k2++) {
        unsigned i = k2 * TT + blockIdx.x * blockDim.x + threadIdx.x;
        bool active = (i < ns);
        unsigned long long pk = active ? sp[i] : 0ull;
        unsigned bk = active ? (((unsigned)(pk >> 32)) >> 12) - BUCKET_BASE : 0u;
        bool pA = active && (bk > B1);
        bool pB = active && (bk == B1);
        agg_push(pA, pk, &ctrl[b * 8 + 2], gA, KTOP, lane);
        agg_push(pB, pk, &ctrl[b * 8 + 3], gB, CAPB, lane);
    }
}

// ---------------- SLOW (guarded) full compact ----------------
__global__ void k_compact(const float* __restrict__ logits, const float* __restrict__ cent,
                          unsigned* __restrict__ ctrl,
                          unsigned long long* __restrict__ candA,
                          unsigned long long* __restrict__ candB) {
    if (ctrl[7] == 0) return;
    int b = blockIdx.y;
    unsigned B1 = ctrl[b * 8 + 0];
    const float4* lg = (const float4*)(logits + (size_t)b * NC);
    const float* cb = cent + (size_t)b * NN;
    const int T4 = NC / 4;
    unsigned long long* gA = candA + (size_t)b * KTOP;
    unsigned long long* gB = candB + (size_t)b * CAPB;
    for (int i = blockIdx.x * blockDim.x + threadIdx.x; i < T4; i += gridDim.x * blockDim.x) {
        float4 v = lg[i];
        int n = i / 20;
        int c4 = (i - n * 20) * 4;
        float ce = cb[n];
        float sv[4] = {v.x, v.y, v.z, v.w};
#pragma unroll
        for (int k = 0; k < 4; k++) {
            float s = sqrtf(sv[k] * ce);
            int c = c4 + k;
            if (c != 0 && s > 0.05f) {
                unsigned key = __float_as_uint(s);
                unsigned bk = (key >> 12) - BUCKET_BASE;
                if (bk >= B1) {
                    unsigned flat = (unsigned)(i * 4 + k);
                    unsigned long long pk = ((unsigned long long)key << 32) | (unsigned)(~flat);
                    if (bk > B1) {
                        unsigned p = atomicAdd(&ctrl[b * 8 + 2], 1u);
                        if (p < KTOP) gA[p] = pk;
                    } else {
                        unsigned p = atomicAdd(&ctrl[b * 8 + 3], 1u);
                        if (p < CAPB) gB[p] = pk;
                    }
                }
            }
        }
    }
}

// ---------------- Resolve boundary bucket exactly ----------------
__global__ void k_boundary(unsigned* __restrict__ ctrl,
                           unsigned long long* __restrict__ candA,
                           const unsigned long long* __restrict__ candB) {
    int b = blockIdx.x;
    int t = threadIdx.x;
    unsigned nA = ctrl[b * 8 + 2];
    if (nA > KTOP) nA = KTOP;
    unsigned nB = ctrl[b * 8 + 3];
    if (nB > CAPB) nB = CAPB;
    int m = (int)KTOP - (int)nA;
    if (m < 0) m = 0;
    __shared__ unsigned long long sB[8192];
    const unsigned long long* gB = candB + (size_t)b * CAPB;
    unsigned long long* gA = candA + (size_t)b * KTOP;
    unsigned nBr = (nB + 255u) & ~255u;
    for (unsigned ii = 0; ii < nBr; ii += 256) {
        unsigned i = ii + (unsigned)t;
        bool act = (i < nB);
        unsigned long long ki = act ? gB[i] : 0ull;
        unsigned rank = 0;
        for (unsigned cb0 = 0; cb0 < nB; cb0 += 8192) {
            unsigned chunk = nB - cb0;
            if (chunk > 8192) chunk = 8192;
            __syncthreads();
            for (unsigned j = (unsigned)t; j < chunk; j += 256) sB[j] = gB[cb0 + j];
            __syncthreads();
            if (act) {
                for (unsigned j = 0; j < chunk; j++) rank += (sB[j] > ki) ? 1u : 0u;
            }
        }
        if (act && rank < (unsigned)m) gA[nA + rank] = ki;
    }
    unsigned take = ((unsigned)m < nB) ? (unsigned)m : nB;
    unsigned filled = nA + take;
    for (unsigned i = filled + (unsigned)t; i < KTOP; i += 256) gA[i] = 0ull;
}

// ---------------- NMS + output: 1024 thr, 4 cand/thread (register-resident) ----------------
__global__ void __launch_bounds__(1024, 1) k_nms(const float* __restrict__ logits,
                                                 const float* __restrict__ regress,
                                                 const float* __restrict__ points,
                                                 const float* __restrict__ cent,
                                                 const unsigned long long* __restrict__ candA,
                                                 float* __restrict__ out) {
    int b = blockIdx.x;
    int t = threadIdx.x;
    const unsigned long long* gA = candA + (size_t)b * KTOP;

    unsigned long long key[4];
    float bx1[4], by1[4], bx2[4], by2[4], ar[4];
    int cls[4];
    unsigned anc[4];
#pragma unroll
    for (int i = 0; i < 4; i++) {
        unsigned long long kk = gA[i * 1024 + t];
        key[i] = kk;
        cls[i] = -1;
        anc[i] = 0xFFFFFFFFu;
        bx1[i] = by1[i] = bx2[i] = by2[i] = ar[i] = 0.f;
        if (kk) {
            unsigned idx = ~(unsigned)kk;
            unsigned a = idx / CC;
            unsigned cc = idx - a * CC;
            anc[i] = a;
            cls[i] = (int)cc;
            float px = points[a * 2 + 0], py = points[a * 2 + 1];
            const float* rg = regress + ((size_t)b * NN + a) * 4;
            float x1 = fminf(fmaxf(px - rg[0], 0.f), 1.f);
            float y1 = fminf(fmaxf(py - rg[1], 0.f), 1.f);
            float x2 = fminf(fmaxf(px + rg[2], 0.f), 1.f);
            float y2 = fminf(fmaxf(py + rg[3], 0.f), 1.f);
            bx1[i] = x1; by1[i] = y1; bx2[i] = x2; by2[i] = y2;
            ar[i] = (x2 - x1) * (y2 - y1);
        }
    }

    __shared__ unsigned long long wkey[16];
    __shared__ float sb[5];   // winner x1,y1,x2,y2,area
    __shared__ int sc;
    __shared__ unsigned sa;
    __shared__ unsigned selA[PROP];
    __shared__ float selB[PROP][4];
    int lane = t & 63, wid = t >> 6;

    for (int p = 0; p < PROP; p++) {
        unsigned long long lmk = 0;
#pragma unroll
        for (int i = 0; i < 4; i++) lmk = key[i] > lmk ? key[i] : lmk;
        unsigned long long rk = lmk;
#pragma unroll
        for (int off = 32; off >= 1; off >>= 1) {
            unsigned long long o = __shfl_xor(rk, off);
            rk = o > rk ? o : rk;
        }
        if (lane == 0) wkey[wid] = rk;
        __syncthreads();
        unsigned long long bk = wkey[0];
#pragma unroll
        for (int w = 1; w < 16; w++) bk = wkey[w] > bk ? wkey[w] : bk;
        if (bk) {
            // winner extraction with STATIC indices (keys unique, exactly one match in block)
#pragma unroll
            for (int i = 0; i < 4; i++) {
                if (key[i] == bk) {
                    sb[0] = bx1[i]; sb[1] = by1[i]; sb[2] = bx2[i]; sb[3] = by2[i]; sb[4] = ar[i];
                    sc = cls[i]; sa = anc[i];
                    key[i] = 0;
                }
            }
        }
        __syncthreads();
        if (t == 0) {
            if (bk) {
                selA[p] = sa;
                selB[p][0] = sb[0]; selB[p][1] = sb[1]; selB[p][2] = sb[2]; selB[p][3] = sb[3];
            } else {
                selA[p] = 0xFFFFFFFFu;
                selB[p][0] = selB[p][1] = selB[p][2] = selB[p][3] = 0.f;
            }
        }
        if (bk) {
            float jx1 = sb[0], jy1 = sb[1], jx2 = sb[2], jy2 = sb[3], ja = sb[4];
            int jc = sc;
#pragma unroll
            for (int i = 0; i < 4; i++) {
                if (cls[i] == jc) {
                    float w = fmaxf(fminf(jx2, bx2[i]) - fmaxf(jx1, bx1[i]), 0.f);
                    float h = fmaxf(fminf(jy2, by2[i]) - fmaxf(jy1, by1[i]), 0.f);
                    float inter = w * h;
                    float uni = ja + ar[i] - inter;
                    float iou = inter / fmaxf(uni, 1e-9f);
                    if (iou > 0.5f) key[i] = 0;
                }
            }
        }
    }
    __syncthreads();

    float* outL = out + (size_t)b * PROP * CC;
    const float* lgb = logits + (size_t)b * NC;
    const float* cb = cent + (size_t)b * NN;
    for (int s = t; s < PROP * CC; s += 1024) {
        int p = s / CC;
        int c = s - p * CC;
        unsigned a = selA[p];
        float v = 0.f;
        if (a != 0xFFFFFFFFu) v = sqrtf(lgb[(size_t)a * CC + c] * cb[a]);
        outL[s] = v;
    }
    float* outB = out + (size_t)BB * PROP * CC + (size_t)b * PROP * 4;
    for (int s = t; s < PROP * 4; s += 1024) {
        outB[s] = selB[s >> 2][s & 3];
    }
}

extern "C" void kernel_launch(void* const* d_in, const int* in_sizes, int n_in,
                              void* d_out, int out_size, void* d_ws, size_t ws_size,
                              hipStream_t stream) {
    const float* logits  = (const float*)d_in[0];
    const float* regress = (const float*)d_in[1];
    const float* points  = (const float*)d_in[2];
    const float* cent    = (const float*)d_in[3];
    float* out = (float*)d_out;

    char* ws = (char*)d_ws;
    unsigned* hist = (unsigned*)ws;
    unsigned* ctrl = (unsigned*)(ws + CTRL_OFF);
    unsigned long long* candA = (unsigned long long*)(ws + CANDA_OFF);
    unsigned long long* candB = (unsigned long long*)(ws + CANDB_OFF);
    unsigned long long* spill = (unsigned long long*)(ws + SPILL_OFF);

    hipMemsetAsync(d_ws, 0, ZERO_BYTES, stream);
    if (ws_size >= WS_NEEDED) {
        k_pass1<<<dim3(512, BB), 256, 0, stream>>>(logits, cent, ctrl, spill);
        k_slowflag<<<1, 64, 0, stream>>>(ctrl);
        k_hist_spill<<<dim3(32, BB), 256, 0, stream>>>(ctrl, spill, hist);
        k_hist<<<dim3(256, BB), 256, 0, stream>>>(logits, cent, hist, ctrl);        // guarded slow path
        k_select<<<BB, 256, 0, stream>>>(hist, ctrl);
        k_compact_fast<<<dim3(32, BB), 256, 0, stream>>>(ctrl, spill, candA, candB);
        k_compact<<<dim3(256, BB), 256, 0, stream>>>(logits, cent, ctrl, candA, candB);  // guarded slow path
    } else {
        hipMemsetAsync(ws + CTRL_OFF + 28, 1, 1, stream);  // force validated full-scan path
        k_hist<<<dim3(256, BB), 256, 0, stream>>>(logits, cent, hist, ctrl);
        k_select<<<BB, 256, 0, stream>>>(hist, ctrl);
        k_compact<<<dim3(256, BB), 256, 0, stream>>>(logits, cent, ctrl, candA, candB);
    }
    k_boundary<<<BB, 256, 0, stream>>>(ctrl, candA, candB);
    k_nms<<<BB, 1024, 0, stream>>>(logits, regress, points, cent, candA, out);
}

// Round 6
// 398.249 us; speedup vs baseline: 2.6404x; 1.3137x over previous
//
#include <hip/hip_runtime.h>
#include <cstdint>
#include <cstddef>

#define BB 4
#define NN 100000
#define CC 80
#define NC (NN * CC)          // 8,000,000
#define KTOP 4096
#define PROP 100
#define HBINS 10248           // buckets for (float_bits>>12) - 0x3D000, covers (0.03125, 1.0]
#define BUCKET_BASE 0x3D000u
#define CAPB 16384
#define SPILLCAP 131072
#define T0BK 0x3F733u         // absolute bucket threshold: s >= 0.94989...
#define SPILL_LO (T0BK - BUCKET_BASE)     // 10035
#define SPILL_BINS (HBINS - SPILL_LO)     // 213
#define P1CAP 1024            // per-block LDS spill buffer entries

// ws layout:
//   [0)        hist  : BB * HBINS * u32 = 163,968 B (zeroed)
//   [163968)   ctrl  : 128 B (zeroed)  b*8+{0:B1,1:cntAbove,2:nA,3:nB,4:nSpill}; ctrl[6]=p1 overflow, ctrl[7]=needFull
//   [164096)   candA : BB * KTOP * u64
//   [295168)   candB : BB * CAPB * u64
//   [819456)   spill : BB * SPILLCAP * u64
#define HIST_BYTES (BB * HBINS * 4)
#define CTRL_OFF   HIST_BYTES
#define ZERO_BYTES (HIST_BYTES + 128)
#define CANDA_OFF  (HIST_BYTES + 128)
#define CANDB_OFF  (CANDA_OFF + BB * KTOP * 8)
#define SPILL_OFF  (CANDB_OFF + BB * CAPB * 8)
#define WS_NEEDED  ((size_t)SPILL_OFF + (size_t)BB * SPILLCAP * 8)

__device__ __forceinline__ void agg_push(bool pred, unsigned long long pk,
                                         unsigned* counter, unsigned long long* buf,
                                         unsigned cap, int lane) {
    unsigned long long m = __ballot(pred);
    if (m) {
        int leader = __ffsll(m) - 1;
        unsigned base = 0;
        if (lane == leader) base = atomicAdd(counter, (unsigned)__popcll(m));
        base = (unsigned)__shfl((int)base, leader);
        if (pred) {
            unsigned pos = base + (unsigned)__popcll(m & ((1ull << lane) - 1ull));
            if (pos < cap) buf[pos] = pk;
        }
    }
}

// ---------------- FAST pass 1: filter s>=bucket(T0BK); LDS-staged spill ----------------
__global__ void k_pass1(const float* __restrict__ logits, const float* __restrict__ cent,
                        unsigned* __restrict__ ctrl, unsigned long long* __restrict__ spill) {
    int b = blockIdx.y;
    __shared__ unsigned long long lbuf[P1CAP];
    __shared__ unsigned lcnt, gbase, lflush;
    if (threadIdx.x == 0) lcnt = 0;
    __syncthreads();
    const float4* lg = (const float4*)(logits + (size_t)b * NC);
    const float* cb = cent + (size_t)b * NN;
    const int T4 = NC / 4;
    for (int i = blockIdx.x * blockDim.x + threadIdx.x; i < T4; i += gridDim.x * blockDim.x) {
        float4 v = lg[i];
        int n = i / 20;
        int c4 = (i - n * 20) * 4;
        float ce = cb[n];
        unsigned k0 = __float_as_uint(sqrtf(v.x * ce));
        unsigned k1 = __float_as_uint(sqrtf(v.y * ce));
        unsigned k2 = __float_as_uint(sqrtf(v.z * ce));
        unsigned k3 = __float_as_uint(sqrtf(v.w * ce));
        bool p0 = (c4 != 0) && ((k0 >> 12) >= T0BK);
        bool p1 = (k1 >> 12) >= T0BK;
        bool p2 = (k2 >> 12) >= T0BK;
        bool p3 = (k3 >> 12) >= T0BK;
        unsigned cnt = (unsigned)p0 + (unsigned)p1 + (unsigned)p2 + (unsigned)p3;
        if (cnt) {
            unsigned q = atomicAdd(&lcnt, cnt);
            unsigned f = (unsigned)i * 4u;
            if (p0) { if (q < P1CAP) lbuf[q] = ((unsigned long long)k0 << 32) | (unsigned)(~(f + 0)); q++; }
            if (p1) { if (q < P1CAP) lbuf[q] = ((unsigned long long)k1 << 32) | (unsigned)(~(f + 1)); q++; }
            if (p2) { if (q < P1CAP) lbuf[q] = ((unsigned long long)k2 << 32) | (unsigned)(~(f + 2)); q++; }
            if (p3) { if (q < P1CAP) lbuf[q] = ((unsigned long long)k3 << 32) | (unsigned)(~(f + 3)); }
        }
    }
    __syncthreads();
    if (threadIdx.x == 0) {
        unsigned n = lcnt;
        if (n > P1CAP) { atomicOr(&ctrl[6], 1u); n = P1CAP; }
        lflush = n;
        gbase = n ? atomicAdd(&ctrl[b * 8 + 4], n) : 0u;
    }
    __syncthreads();
    unsigned long long* sp = spill + (size_t)b * SPILLCAP;
    unsigned n = lflush, g0 = gbase;
    for (unsigned i = threadIdx.x; i < n; i += blockDim.x) {
        unsigned pos = g0 + i;
        if (pos < SPILLCAP) sp[pos] = lbuf[i];
    }
}

// ---------------- decide fast/slow path ----------------
__global__ void k_slowflag(unsigned* __restrict__ ctrl) {
    if (threadIdx.x == 0 && blockIdx.x == 0) {
        unsigned f = ctrl[6] ? 1u : 0u;
        for (int b = 0; b < BB; b++) {
            unsigned ns = ctrl[b * 8 + 4];
            if (ns < KTOP || ns > SPILLCAP) f = 1;
        }
        ctrl[7] = f;
    }
}

// ---------------- FAST: histogram the spill buffer ----------------
__global__ void k_hist_spill(const unsigned* __restrict__ ctrl,
                             const unsigned long long* __restrict__ spill,
                             unsigned* __restrict__ hist) {
    if (ctrl[7]) return;
    int b = blockIdx.y;
    __shared__ unsigned lh[SPILL_BINS];
    for (int i = threadIdx.x; i < SPILL_BINS; i += blockDim.x) lh[i] = 0;
    __syncthreads();
    unsigned ns = ctrl[b * 8 + 4];
    if (ns > SPILLCAP) ns = SPILLCAP;
    const unsigned long long* sp = spill + (size_t)b * SPILLCAP;
    for (unsigned i = blockIdx.x * blockDim.x + threadIdx.x; i < ns; i += gridDim.x * blockDim.x) {
        unsigned bits = (unsigned)(sp[i] >> 32);
        atomicAdd(&lh[(bits >> 12) - T0BK], 1u);
    }
    __syncthreads();
    unsigned* gh = hist + (size_t)b * HBINS + SPILL_LO;
    for (int i = threadIdx.x; i < SPILL_BINS; i += blockDim.x) {
        unsigned c = lh[i];
        if (c) atomicAdd(&gh[i], c);
    }
}

// ---------------- SLOW (guarded) full histogram ----------------
__global__ void k_hist(const float* __restrict__ logits, const float* __restrict__ cent,
                       unsigned* __restrict__ hist, const unsigned* __restrict__ ctrl) {
    if (ctrl[7] == 0) return;
    int b = blockIdx.y;
    __shared__ unsigned lh[HBINS];
    for (int i = threadIdx.x; i < HBINS; i += blockDim.x) lh[i] = 0;
    __syncthreads();
    const float4* lg = (const float4*)(logits + (size_t)b * NC);
    const float* cb = cent + (size_t)b * NN;
    const int T4 = NC / 4;
    for (int i = blockIdx.x * blockDim.x + threadIdx.x; i < T4; i += gridDim.x * blockDim.x) {
        float4 v = lg[i];
        int n = i / 20;
        int c4 = (i - n * 20) * 4;
        float ce = cb[n];
        float s;
        s = sqrtf(v.x * ce);
        if (c4 != 0 && s > 0.05f) atomicAdd(&lh[(__float_as_uint(s) >> 12) - BUCKET_BASE], 1u);
        s = sqrtf(v.y * ce);
        if (s > 0.05f) atomicAdd(&lh[(__float_as_uint(s) >> 12) - BUCKET_BASE], 1u);
        s = sqrtf(v.z * ce);
        if (s > 0.05f) atomicAdd(&lh[(__float_as_uint(s) >> 12) - BUCKET_BASE], 1u);
        s = sqrtf(v.w * ce);
        if (s > 0.05f) atomicAdd(&lh[(__float_as_uint(s) >> 12) - BUCKET_BASE], 1u);
    }
    __syncthreads();
    unsigned* gh = hist + (size_t)b * HBINS;
    for (int i = threadIdx.x; i < HBINS; i += blockDim.x) {
        unsigned c = lh[i];
        if (c) atomicAdd(&gh[i], c);
    }
}

// ---------------- Find boundary bucket B1 per batch ----------------
__global__ void k_select(const unsigned* __restrict__ hist, unsigned* __restrict__ ctrl) {
    int b = blockIdx.x;
    int t = threadIdx.x;
    const unsigned* h = hist + (size_t)b * HBINS;
    __shared__ unsigned ssum[256];
    const int CH = (HBINS + 255) / 256;  // 41
    unsigned acc0 = 0;
    for (int i = 0; i < CH; i++) {
        int idx = t * CH + i;
        if (idx < HBINS) acc0 += h[idx];
    }
    ssum[t] = acc0;
    __syncthreads();
    for (int off = 1; off < 256; off <<= 1) {
        unsigned v = (t + off < 256) ? ssum[t + off] : 0u;
        __syncthreads();
        ssum[t] += v;
        __syncthreads();
    }
    unsigned acc = (t < 255) ? ssum[t + 1] : 0u;
    for (int i = CH - 1; i >= 0; i--) {
        int idx = t * CH + i;
        if (idx >= HBINS) continue;
        unsigned cnt = h[idx];
        unsigned na = acc + cnt;
        if (na >= KTOP && acc < KTOP) {
            ctrl[b * 8 + 0] = (unsigned)idx;
            ctrl[b * 8 + 1] = acc;
        }
        acc = na;
    }
}

// ---------------- FAST: partition spill by B1 ----------------
__global__ void k_compact_fast(unsigned* __restrict__ ctrl,
                               const unsigned long long* __restrict__ spill,
                               unsigned long long* __restrict__ candA,
                               unsigned long long* __restrict__ candB) {
    if (ctrl[7]) return;
    int b = blockIdx.y;
    unsigned B1 = ctrl[b * 8 + 0];
    unsigned ns = ctrl[b * 8 + 4];
    if (ns > SPILLCAP) ns = SPILLCAP;
    const unsigned long long* sp = spill + (size_t)b * SPILLCAP;
    unsigned long long* gA = candA + (size_t)b * KTOP;
    unsigned long long* gB = candB + (size_t)b * CAPB;
    int lane = threadIdx.x & 63;
    unsigned TT = gridDim.x * blockDim.x;
    unsigned iters = (ns + TT - 1) / TT;
    for (unsigned k2 = 0; k2 < iters; k2++) {
        unsigned i = k2 * TT + blockIdx.x * blockDim.x + threadIdx.x;
        bool active = (i < ns);
        unsigned long long pk = active ? sp[i] : 0ull;
        unsigned bk = active ? (((unsigned)(pk >> 32)) >> 12) - BUCKET_BASE : 0u;
        bool pA = active && (bk > B1);
        bool pB = active && (bk == B1);
        agg_push(pA, pk, &ctrl[b * 8 + 2], gA, KTOP, lane);
        agg_push(pB, pk, &ctrl[b * 8 + 3], gB, CAPB, lane);
    }
}

// ---------------- SLOW (guarded) full compact ----------------
__global__ void k_compact(const float* __restrict__ logits, const float* __restrict__ cent,
                          unsigned* __restrict__ ctrl,
                          unsigned long long* __restrict__ candA,
                          unsigned long long* __restrict__ candB) {
    if (ctrl[7] == 0) return;
    int b = blockIdx.y;
    unsigned B1 = ctrl[b * 8 + 0];
    const float4* lg = (const float4*)(logits + (size_t)b * NC);
    const float* cb = cent + (size_t)b * NN;
    const int T4 = NC / 4;
    unsigned long long* gA = candA + (size_t)b * KTOP;
    unsigned long long* gB = candB + (size_t)b * CAPB;
    for (int i = blockIdx.x * blockDim.x + threadIdx.x; i < T4; i += gridDim.x * blockDim.x) {
        float4 v = lg[i];
        int n = i / 20;
        int c4 = (i - n * 20) * 4;
        float ce = cb[n];
        float sv[4] = {v.x, v.y, v.z, v.w};
#pragma unroll
        for (int k = 0; k < 4; k++) {
            float s = sqrtf(sv[k] * ce);
            int c = c4 + k;
            if (c != 0 && s > 0.05f) {
                unsigned key = __float_as_uint(s);
                unsigned bk = (key >> 12) - BUCKET_BASE;
                if (bk >= B1) {
                    unsigned flat = (unsigned)(i * 4 + k);
                    unsigned long long pk = ((unsigned long long)key << 32) | (unsigned)(~flat);
                    if (bk > B1) {
                        unsigned p = atomicAdd(&ctrl[b * 8 + 2], 1u);
                        if (p < KTOP) gA[p] = pk;
                    } else {
                        unsigned p = atomicAdd(&ctrl[b * 8 + 3], 1u);
                        if (p < CAPB) gB[p] = pk;
                    }
                }
            }
        }
    }
}

// ---------------- Resolve boundary bucket exactly ----------------
__global__ void k_boundary(unsigned* __restrict__ ctrl,
                           unsigned long long* __restrict__ candA,
                           const unsigned long long* __restrict__ candB) {
    int b = blockIdx.x;
    int t = threadIdx.x;
    unsigned nA = ctrl[b * 8 + 2];
    if (nA > KTOP) nA = KTOP;
    unsigned nB = ctrl[b * 8 + 3];
    if (nB > CAPB) nB = CAPB;
    int m = (int)KTOP - (int)nA;
    if (m < 0) m = 0;
    __shared__ unsigned long long sB[8192];
    const unsigned long long* gB = candB + (size_t)b * CAPB;
    unsigned long long* gA = candA + (size_t)b * KTOP;
    unsigned nBr = (nB + 255u) & ~255u;
    for (unsigned ii = 0; ii < nBr; ii += 256) {
        unsigned i = ii + (unsigned)t;
        bool act = (i < nB);
        unsigned long long ki = act ? gB[i] : 0ull;
        unsigned rank = 0;
        for (unsigned cb0 = 0; cb0 < nB; cb0 += 8192) {
            unsigned chunk = nB - cb0;
            if (chunk > 8192) chunk = 8192;
            __syncthreads();
            for (unsigned j = (unsigned)t; j < chunk; j += 256) sB[j] = gB[cb0 + j];
            __syncthreads();
            if (act) {
                for (unsigned j = 0; j < chunk; j++) rank += (sB[j] > ki) ? 1u : 0u;
            }
        }
        if (act && rank < (unsigned)m) gA[nA + rank] = ki;
    }
    unsigned take = ((unsigned)m < nB) ? (unsigned)m : nB;
    unsigned filled = nA + take;
    for (unsigned i = filled + (unsigned)t; i < KTOP; i += 256) gA[i] = 0ull;
}

// ---------------- NMS: bitonic sort (LDS) + single-wave sorted scan ----------------
__global__ void __launch_bounds__(256, 1) k_nms(const float* __restrict__ logits,
                                                const float* __restrict__ regress,
                                                const float* __restrict__ points,
                                                const float* __restrict__ cent,
                                                const unsigned long long* __restrict__ candA,
                                                float* __restrict__ out) {
    int b = blockIdx.x;
    int t = threadIdx.x;
    const unsigned long long* gA = candA + (size_t)b * KTOP;

    __shared__ unsigned long long sk[KTOP];   // 32 KB sorted keys
    __shared__ float4 sbox[KTOP];             // 64 KB decoded clipped boxes
    __shared__ float4 kbox[PROP];             // kept boxes (selection order)
    __shared__ unsigned kcls[PROP];
    __shared__ unsigned selAnc[PROP];
    __shared__ unsigned scnt;

    // load keys + init kept arrays
    for (int i = t; i < KTOP; i += 256) sk[i] = gA[i];
    if (t < PROP) { selAnc[t] = 0xFFFFFFFFu; kcls[t] = 0xFFFFFFFFu; }
    if (t == 0) scnt = 0;
    __syncthreads();

    // bitonic sort descending (keys unique except 0-pads which sink to the end)
    for (unsigned k = 2; k <= KTOP; k <<= 1) {
        for (unsigned j = k >> 1; j > 0; j >>= 1) {
            for (unsigned t2 = t; t2 < KTOP / 2; t2 += 256) {
                unsigned i = ((t2 & ~(j - 1)) << 1) | (t2 & (j - 1));
                unsigned p2 = i + j;
                bool dir = ((i & k) == 0);  // true -> descending block
                unsigned long long a = sk[i], c = sk[p2];
                if ((a < c) == dir) { sk[i] = c; sk[p2] = a; }
            }
            __syncthreads();
        }
    }

    // decode boxes for sorted candidates
    for (int i = t; i < KTOP; i += 256) {
        unsigned long long kk = sk[i];
        float4 bx = {0.f, 0.f, 0.f, 0.f};
        if (kk) {
            unsigned flat = ~(unsigned)kk;
            unsigned a = flat / CC;
            float px = points[a * 2 + 0], py = points[a * 2 + 1];
            const float* rg = regress + ((size_t)b * NN + a) * 4;
            bx.x = fminf(fmaxf(px - rg[0], 0.f), 1.f);
            bx.y = fminf(fmaxf(py - rg[1], 0.f), 1.f);
            bx.z = fminf(fmaxf(px + rg[2], 0.f), 1.f);
            bx.w = fminf(fmaxf(py + rg[3], 0.f), 1.f);
        }
        sbox[i] = bx;
    }
    __syncthreads();

    // single-wave sorted scan: keep i iff no earlier KEPT same-class box with IoU>0.5
    if (t < 64) {
        int lane = t;
        int cnt = 0;
        for (int i = 0; i < KTOP && cnt < PROP; i++) {
            unsigned long long kk = sk[i];
            if (kk == 0) break;
            unsigned flat = ~(unsigned)kk;
            unsigned a = flat / CC;
            unsigned ccls = flat - a * CC;
            float4 cb4 = sbox[i];
            float ca = (cb4.z - cb4.x) * (cb4.w - cb4.y);
            bool sup = false;
            if (lane < cnt) {
                float4 kb = kbox[lane];
                if (kcls[lane] == ccls) {
                    float w = fmaxf(fminf(cb4.z, kb.z) - fmaxf(cb4.x, kb.x), 0.f);
                    float h = fmaxf(fminf(cb4.w, kb.w) - fmaxf(cb4.y, kb.y), 0.f);
                    float inter = w * h;
                    float ka = (kb.z - kb.x) * (kb.w - kb.y);
                    float iou = inter / fmaxf(ca + ka - inter, 1e-9f);
                    sup = iou > 0.5f;
                }
            }
            if (lane + 64 < cnt) {
                float4 kb = kbox[lane + 64];
                if (kcls[lane + 64] == ccls) {
                    float w = fmaxf(fminf(cb4.z, kb.z) - fmaxf(cb4.x, kb.x), 0.f);
                    float h = fmaxf(fminf(cb4.w, kb.w) - fmaxf(cb4.y, kb.y), 0.f);
                    float inter = w * h;
                    float ka = (kb.z - kb.x) * (kb.w - kb.y);
                    float iou = inter / fmaxf(ca + ka - inter, 1e-9f);
                    sup = sup || (iou > 0.5f);
                }
            }
            if (!__any(sup)) {
                if (lane == 0) {
                    kbox[cnt] = cb4;
                    kcls[cnt] = ccls;
                    selAnc[cnt] = a;
                }
                cnt++;
            }
        }
        if (lane == 0) scnt = (unsigned)cnt;
    }
    __syncthreads();

    // outputs: out_logit [B][PROP][CC] then out_box [B][PROP][4]
    unsigned nk = scnt;
    float* outL = out + (size_t)b * PROP * CC;
    const float* lgb = logits + (size_t)b * NC;
    const float* cb = cent + (size_t)b * NN;
    for (int s = t; s < PROP * CC; s += 256) {
        int p = s / CC;
        int c = s - p * CC;
        float v = 0.f;
        if ((unsigned)p < nk) {
            unsigned a = selAnc[p];
            v = sqrtf(lgb[(size_t)a * CC + c] * cb[a]);
        }
        outL[s] = v;
    }
    float* outB = out + (size_t)BB * PROP * CC + (size_t)b * PROP * 4;
    for (int s = t; s < PROP * 4; s += 256) {
        int p = s >> 2;
        float v = 0.f;
        if ((unsigned)p < nk) v = ((const float*)&kbox[p])[s & 3];
        outB[s] = v;
    }
}

extern "C" void kernel_launch(void* const* d_in, const int* in_sizes, int n_in,
                              void* d_out, int out_size, void* d_ws, size_t ws_size,
                              hipStream_t stream) {
    const float* logits  = (const float*)d_in[0];
    const float* regress = (const float*)d_in[1];
    const float* points  = (const float*)d_in[2];
    const float* cent    = (const float*)d_in[3];
    float* out = (float*)d_out;

    char* ws = (char*)d_ws;
    unsigned* hist = (unsigned*)ws;
    unsigned* ctrl = (unsigned*)(ws + CTRL_OFF);
    unsigned long long* candA = (unsigned long long*)(ws + CANDA_OFF);
    unsigned long long* candB = (unsigned long long*)(ws + CANDB_OFF);
    unsigned long long* spill = (unsigned long long*)(ws + SPILL_OFF);

    hipMemsetAsync(d_ws, 0, ZERO_BYTES, stream);
    if (ws_size >= WS_NEEDED) {
        k_pass1<<<dim3(512, BB), 256, 0, stream>>>(logits, cent, ctrl, spill);
        k_slowflag<<<1, 64, 0, stream>>>(ctrl);
        k_hist_spill<<<dim3(32, BB), 256, 0, stream>>>(ctrl, spill, hist);
        k_hist<<<dim3(256, BB), 256, 0, stream>>>(logits, cent, hist, ctrl);        // guarded slow path
        k_select<<<BB, 256, 0, stream>>>(hist, ctrl);
        k_compact_fast<<<dim3(32, BB), 256, 0, stream>>>(ctrl, spill, candA, candB);
        k_compact<<<dim3(256, BB), 256, 0, stream>>>(logits, cent, ctrl, candA, candB);  // guarded slow path
    } else {
        hipMemsetAsync(ws + CTRL_OFF + 28, 1, 1, stream);  // force validated full-scan path
        k_hist<<<dim3(256, BB), 256, 0, stream>>>(logits, cent, hist, ctrl);
        k_select<<<BB, 256, 0, stream>>>(hist, ctrl);
        k_compact<<<dim3(256, BB), 256, 0, stream>>>(logits, cent, ctrl, candA, candB);
    }
    k_boundary<<<BB, 256, 0, stream>>>(ctrl, candA, candB);
    k_nms<<<BB, 256, 0, stream>>>(logits, regress, points, cent, candA, out);
}

// Round 7
// 328.966 us; speedup vs baseline: 3.1965x; 1.2106x over previous
//
#include <hip/hip_runtime.h>
#include <cstdint>
#include <cstddef>

#define BB 4
#define NN 100000
#define CC 80
#define NC (NN * CC)          // 8,000,000
#define KTOP 4096
#define PROP 100
#define HBINS 10248           // buckets for (float_bits>>12) - 0x3D000, covers (0.03125, 1.0]
#define BUCKET_BASE 0x3D000u
#define CAPB 16384
#define SPILLCAP 131072
#define T0BK 0x3F733u         // absolute bucket threshold: s >= 0.94989...
#define SPILL_LO (T0BK - BUCKET_BASE)     // 10035
#define SPILL_BINS (HBINS - SPILL_LO)     // 213
#define P1CAP 1024            // per-block LDS spill buffer entries
#define NSEL 512              // partial-sort target for NMS

// ws layout:
//   [0)        hist  : BB * HBINS * u32 = 163,968 B (zeroed)
//   [163968)   ctrl  : 128 B (zeroed)  b*8+{0:B1,1:cntAbove,2:nA,3:nB,4:nSpill}; ctrl[6]=p1 overflow, ctrl[7]=needFull
//   [164096)   candA : BB * KTOP * u64
//   [295168)   candB : BB * CAPB * u64
//   [819456)   spill : BB * SPILLCAP * u64
#define HIST_BYTES (BB * HBINS * 4)
#define CTRL_OFF   HIST_BYTES
#define ZERO_BYTES (HIST_BYTES + 128)
#define CANDA_OFF  (HIST_BYTES + 128)
#define CANDB_OFF  (CANDA_OFF + BB * KTOP * 8)
#define SPILL_OFF  (CANDB_OFF + BB * CAPB * 8)
#define WS_NEEDED  ((size_t)SPILL_OFF + (size_t)BB * SPILLCAP * 8)

__device__ __forceinline__ void agg_push(bool pred, unsigned long long pk,
                                         unsigned* counter, unsigned long long* buf,
                                         unsigned cap, int lane) {
    unsigned long long m = __ballot(pred);
    if (m) {
        int leader = __ffsll(m) - 1;
        unsigned base = 0;
        if (lane == leader) base = atomicAdd(counter, (unsigned)__popcll(m));
        base = (unsigned)__shfl((int)base, leader);
        if (pred) {
            unsigned pos = base + (unsigned)__popcll(m & ((1ull << lane) - 1ull));
            if (pos < cap) buf[pos] = pk;
        }
    }
}

// ---------------- FAST pass 1: filter s>=bucket(T0BK); LDS-staged spill ----------------
__global__ void k_pass1(const float* __restrict__ logits, const float* __restrict__ cent,
                        unsigned* __restrict__ ctrl, unsigned long long* __restrict__ spill) {
    int b = blockIdx.y;
    __shared__ unsigned long long lbuf[P1CAP];
    __shared__ unsigned lcnt, gbase, lflush;
    if (threadIdx.x == 0) lcnt = 0;
    __syncthreads();
    const float4* lg = (const float4*)(logits + (size_t)b * NC);
    const float* cb = cent + (size_t)b * NN;
    const int T4 = NC / 4;
    for (int i = blockIdx.x * blockDim.x + threadIdx.x; i < T4; i += gridDim.x * blockDim.x) {
        float4 v = lg[i];
        int n = i / 20;
        int c4 = (i - n * 20) * 4;
        float ce = cb[n];
        unsigned k0 = __float_as_uint(sqrtf(v.x * ce));
        unsigned k1 = __float_as_uint(sqrtf(v.y * ce));
        unsigned k2 = __float_as_uint(sqrtf(v.z * ce));
        unsigned k3 = __float_as_uint(sqrtf(v.w * ce));
        bool p0 = (c4 != 0) && ((k0 >> 12) >= T0BK);
        bool p1 = (k1 >> 12) >= T0BK;
        bool p2 = (k2 >> 12) >= T0BK;
        bool p3 = (k3 >> 12) >= T0BK;
        unsigned cnt = (unsigned)p0 + (unsigned)p1 + (unsigned)p2 + (unsigned)p3;
        if (cnt) {
            unsigned q = atomicAdd(&lcnt, cnt);
            unsigned f = (unsigned)i * 4u;
            if (p0) { if (q < P1CAP) lbuf[q] = ((unsigned long long)k0 << 32) | (unsigned)(~(f + 0)); q++; }
            if (p1) { if (q < P1CAP) lbuf[q] = ((unsigned long long)k1 << 32) | (unsigned)(~(f + 1)); q++; }
            if (p2) { if (q < P1CAP) lbuf[q] = ((unsigned long long)k2 << 32) | (unsigned)(~(f + 2)); q++; }
            if (p3) { if (q < P1CAP) lbuf[q] = ((unsigned long long)k3 << 32) | (unsigned)(~(f + 3)); }
        }
    }
    __syncthreads();
    if (threadIdx.x == 0) {
        unsigned n = lcnt;
        if (n > P1CAP) { atomicOr(&ctrl[6], 1u); n = P1CAP; }
        lflush = n;
        gbase = n ? atomicAdd(&ctrl[b * 8 + 4], n) : 0u;
    }
    __syncthreads();
    unsigned long long* sp = spill + (size_t)b * SPILLCAP;
    unsigned n = lflush, g0 = gbase;
    for (unsigned i = threadIdx.x; i < n; i += blockDim.x) {
        unsigned pos = g0 + i;
        if (pos < SPILLCAP) sp[pos] = lbuf[i];
    }
}

// ---------------- decide fast/slow path ----------------
__global__ void k_slowflag(unsigned* __restrict__ ctrl) {
    if (threadIdx.x == 0 && blockIdx.x == 0) {
        unsigned f = ctrl[6] ? 1u : 0u;
        for (int b = 0; b < BB; b++) {
            unsigned ns = ctrl[b * 8 + 4];
            if (ns < KTOP || ns > SPILLCAP) f = 1;
        }
        ctrl[7] = f;
    }
}

// ---------------- FAST: histogram the spill buffer ----------------
__global__ void k_hist_spill(const unsigned* __restrict__ ctrl,
                             const unsigned long long* __restrict__ spill,
                             unsigned* __restrict__ hist) {
    if (ctrl[7]) return;
    int b = blockIdx.y;
    __shared__ unsigned lh[SPILL_BINS];
    for (int i = threadIdx.x; i < SPILL_BINS; i += blockDim.x) lh[i] = 0;
    __syncthreads();
    unsigned ns = ctrl[b * 8 + 4];
    if (ns > SPILLCAP) ns = SPILLCAP;
    const unsigned long long* sp = spill + (size_t)b * SPILLCAP;
    for (unsigned i = blockIdx.x * blockDim.x + threadIdx.x; i < ns; i += gridDim.x * blockDim.x) {
        unsigned bits = (unsigned)(sp[i] >> 32);
        atomicAdd(&lh[(bits >> 12) - T0BK], 1u);
    }
    __syncthreads();
    unsigned* gh = hist + (size_t)b * HBINS + SPILL_LO;
    for (int i = threadIdx.x; i < SPILL_BINS; i += blockDim.x) {
        unsigned c = lh[i];
        if (c) atomicAdd(&gh[i], c);
    }
}

// ---------------- SLOW (guarded) full histogram ----------------
__global__ void k_hist(const float* __restrict__ logits, const float* __restrict__ cent,
                       unsigned* __restrict__ hist, const unsigned* __restrict__ ctrl) {
    if (ctrl[7] == 0) return;
    int b = blockIdx.y;
    __shared__ unsigned lh[HBINS];
    for (int i = threadIdx.x; i < HBINS; i += blockDim.x) lh[i] = 0;
    __syncthreads();
    const float4* lg = (const float4*)(logits + (size_t)b * NC);
    const float* cb = cent + (size_t)b * NN;
    const int T4 = NC / 4;
    for (int i = blockIdx.x * blockDim.x + threadIdx.x; i < T4; i += gridDim.x * blockDim.x) {
        float4 v = lg[i];
        int n = i / 20;
        int c4 = (i - n * 20) * 4;
        float ce = cb[n];
        float s;
        s = sqrtf(v.x * ce);
        if (c4 != 0 && s > 0.05f) atomicAdd(&lh[(__float_as_uint(s) >> 12) - BUCKET_BASE], 1u);
        s = sqrtf(v.y * ce);
        if (s > 0.05f) atomicAdd(&lh[(__float_as_uint(s) >> 12) - BUCKET_BASE], 1u);
        s = sqrtf(v.z * ce);
        if (s > 0.05f) atomicAdd(&lh[(__float_as_uint(s) >> 12) - BUCKET_BASE], 1u);
        s = sqrtf(v.w * ce);
        if (s > 0.05f) atomicAdd(&lh[(__float_as_uint(s) >> 12) - BUCKET_BASE], 1u);
    }
    __syncthreads();
    unsigned* gh = hist + (size_t)b * HBINS;
    for (int i = threadIdx.x; i < HBINS; i += blockDim.x) {
        unsigned c = lh[i];
        if (c) atomicAdd(&gh[i], c);
    }
}

// ---------------- Find boundary bucket B1 per batch ----------------
__global__ void k_select(const unsigned* __restrict__ hist, unsigned* __restrict__ ctrl) {
    int b = blockIdx.x;
    int t = threadIdx.x;
    const unsigned* h = hist + (size_t)b * HBINS;
    __shared__ unsigned ssum[256];
    const int CH = (HBINS + 255) / 256;  // 41
    unsigned acc0 = 0;
    for (int i = 0; i < CH; i++) {
        int idx = t * CH + i;
        if (idx < HBINS) acc0 += h[idx];
    }
    ssum[t] = acc0;
    __syncthreads();
    for (int off = 1; off < 256; off <<= 1) {
        unsigned v = (t + off < 256) ? ssum[t + off] : 0u;
        __syncthreads();
        ssum[t] += v;
        __syncthreads();
    }
    unsigned acc = (t < 255) ? ssum[t + 1] : 0u;
    for (int i = CH - 1; i >= 0; i--) {
        int idx = t * CH + i;
        if (idx >= HBINS) continue;
        unsigned cnt = h[idx];
        unsigned na = acc + cnt;
        if (na >= KTOP && acc < KTOP) {
            ctrl[b * 8 + 0] = (unsigned)idx;
            ctrl[b * 8 + 1] = acc;
        }
        acc = na;
    }
}

// ---------------- FAST: partition spill by B1 ----------------
__global__ void k_compact_fast(unsigned* __restrict__ ctrl,
                               const unsigned long long* __restrict__ spill,
                               unsigned long long* __restrict__ candA,
                               unsigned long long* __restrict__ candB) {
    if (ctrl[7]) return;
    int b = blockIdx.y;
    unsigned B1 = ctrl[b * 8 + 0];
    unsigned ns = ctrl[b * 8 + 4];
    if (ns > SPILLCAP) ns = SPILLCAP;
    const unsigned long long* sp = spill + (size_t)b * SPILLCAP;
    unsigned long long* gA = candA + (size_t)b * KTOP;
    unsigned long long* gB = candB + (size_t)b * CAPB;
    int lane = threadIdx.x & 63;
    unsigned TT = gridDim.x * blockDim.x;
    unsigned iters = (ns + TT - 1) / TT;
    for (unsigned k2 = 0; k2 < iters; k2++) {
        unsigned i = k2 * TT + blockIdx.x * blockDim.x + threadIdx.x;
        bool active = (i < ns);
        unsigned long long pk = active ? sp[i] : 0ull;
        unsigned bk = active ? (((unsigned)(pk >> 32)) >> 12) - BUCKET_BASE : 0u;
        bool pA = active && (bk > B1);
        bool pB = active && (bk == B1);
        agg_push(pA, pk, &ctrl[b * 8 + 2], gA, KTOP, lane);
        agg_push(pB, pk, &ctrl[b * 8 + 3], gB, CAPB, lane);
    }
}

// ---------------- SLOW (guarded) full compact ----------------
__global__ void k_compact(const float* __restrict__ logits, const float* __restrict__ cent,
                          unsigned* __restrict__ ctrl,
                          unsigned long long* __restrict__ candA,
                          unsigned long long* __restrict__ candB) {
    if (ctrl[7] == 0) return;
    int b = blockIdx.y;
    unsigned B1 = ctrl[b * 8 + 0];
    const float4* lg = (const float4*)(logits + (size_t)b * NC);
    const float* cb = cent + (size_t)b * NN;
    const int T4 = NC / 4;
    unsigned long long* gA = candA + (size_t)b * KTOP;
    unsigned long long* gB = candB + (size_t)b * CAPB;
    for (int i = blockIdx.x * blockDim.x + threadIdx.x; i < T4; i += gridDim.x * blockDim.x) {
        float4 v = lg[i];
        int n = i / 20;
        int c4 = (i - n * 20) * 4;
        float ce = cb[n];
        float sv[4] = {v.x, v.y, v.z, v.w};
#pragma unroll
        for (int k = 0; k < 4; k++) {
            float s = sqrtf(sv[k] * ce);
            int c = c4 + k;
            if (c != 0 && s > 0.05f) {
                unsigned key = __float_as_uint(s);
                unsigned bk = (key >> 12) - BUCKET_BASE;
                if (bk >= B1) {
                    unsigned flat = (unsigned)(i * 4 + k);
                    unsigned long long pk = ((unsigned long long)key << 32) | (unsigned)(~flat);
                    if (bk > B1) {
                        unsigned p = atomicAdd(&ctrl[b * 8 + 2], 1u);
                        if (p < KTOP) gA[p] = pk;
                    } else {
                        unsigned p = atomicAdd(&ctrl[b * 8 + 3], 1u);
                        if (p < CAPB) gB[p] = pk;
                    }
                }
            }
        }
    }
}

// ---------------- Resolve boundary bucket exactly ----------------
__global__ void k_boundary(unsigned* __restrict__ ctrl,
                           unsigned long long* __restrict__ candA,
                           const unsigned long long* __restrict__ candB) {
    int b = blockIdx.x;
    int t = threadIdx.x;
    unsigned nA = ctrl[b * 8 + 2];
    if (nA > KTOP) nA = KTOP;
    unsigned nB = ctrl[b * 8 + 3];
    if (nB > CAPB) nB = CAPB;
    int m = (int)KTOP - (int)nA;
    if (m < 0) m = 0;
    __shared__ unsigned long long sB[8192];
    const unsigned long long* gB = candB + (size_t)b * CAPB;
    unsigned long long* gA = candA + (size_t)b * KTOP;
    unsigned nBr = (nB + 255u) & ~255u;
    for (unsigned ii = 0; ii < nBr; ii += 256) {
        unsigned i = ii + (unsigned)t;
        bool act = (i < nB);
        unsigned long long ki = act ? gB[i] : 0ull;
        unsigned rank = 0;
        for (unsigned cb0 = 0; cb0 < nB; cb0 += 8192) {
            unsigned chunk = nB - cb0;
            if (chunk > 8192) chunk = 8192;
            __syncthreads();
            for (unsigned j = (unsigned)t; j < chunk; j += 256) sB[j] = gB[cb0 + j];
            __syncthreads();
            if (act) {
                for (unsigned j = 0; j < chunk; j++) rank += (sB[j] > ki) ? 1u : 0u;
            }
        }
        if (act && rank < (unsigned)m) gA[nA + rank] = ki;
    }
    unsigned take = ((unsigned)m < nB) ? (unsigned)m : nB;
    unsigned filled = nA + take;
    for (unsigned i = filled + (unsigned)t; i < KTOP; i += 256) gA[i] = 0ull;
}

// ---------------- NMS: partial top-S select + small bitonic + reg-cached scan ----------------
__global__ void __launch_bounds__(256, 1) k_nms(const float* __restrict__ logits,
                                                const float* __restrict__ regress,
                                                const float* __restrict__ points,
                                                const float* __restrict__ cent,
                                                const unsigned long long* __restrict__ candA,
                                                float* __restrict__ out) {
    int b = blockIdx.x;
    int t = threadIdx.x;
    const unsigned long long* gA = candA + (size_t)b * KTOP;

    __shared__ unsigned long long sk[KTOP];    // raw keys (32 KB)
    __shared__ unsigned long long sel[KTOP];   // selected+sorted keys (32 KB)
    __shared__ float4 sbox[KTOP];              // boxes of selected candidates (64 KB)
    __shared__ unsigned hist2[SPILL_BINS];
    __shared__ unsigned sc[8];                 // 0:total 1:S 2:Bq 3:kept 4:exhaust
    __shared__ float4 kbox[PROP];
    __shared__ unsigned selAnc[PROP];

    // load keys, build bucket histogram + nonzero count
    for (int i = t; i < SPILL_BINS; i += 256) hist2[i] = 0;
    if (t < 8) sc[t] = 0;
    __syncthreads();
    for (int i = t; i < KTOP; i += 256) {
        unsigned long long kk = gA[i];
        sk[i] = kk;
        if (kk) {
            int bkt = (int)((unsigned)(kk >> 32) >> 12) - (int)T0BK;
            bkt = bkt < 0 ? 0 : bkt;           // slow-path keys clamp to lowest bucket
            atomicAdd(&hist2[bkt], 1u);
            atomicAdd(&sc[0], 1u);
        }
    }
    __syncthreads();

    for (int round = 0; round < 2; round++) {
        unsigned target = round == 0 ? NSEL : KTOP;
        // threshold bucket: smallest Bq with suffix(Bq) >= min(target,total)
        if (t == 0) {
            unsigned total = sc[0];
            unsigned tgt = target < total ? target : total;
            int bq = SPILL_BINS;  // select none if tgt==0
            if (tgt > 0) {
                unsigned acc = 0;
                for (int i = SPILL_BINS - 1; i >= 0; i--) {
                    acc += hist2[i];
                    if (acc >= tgt) { bq = i; break; }
                }
            }
            sc[2] = (unsigned)bq;
            sc[1] = 0;
            sc[3] = 0;
            sc[4] = 0;
        }
        __syncthreads();
        int bq = (int)sc[2];
        // compact selected (bucket >= bq)
        for (int i = t; i < KTOP; i += 256) {
            unsigned long long kk = sk[i];
            if (kk) {
                int bkt = (int)((unsigned)(kk >> 32) >> 12) - (int)T0BK;
                bkt = bkt < 0 ? 0 : bkt;
                if (bkt >= bq) {
                    unsigned p = atomicAdd(&sc[1], 1u);
                    sel[p] = kk;
                }
            }
        }
        __syncthreads();
        unsigned S = sc[1];
        unsigned P2 = 2;
        while (P2 < S) P2 <<= 1;
        for (unsigned i = S + t; i < P2; i += 256) sel[i] = 0ull;
        __syncthreads();
        // bitonic sort descending
        for (unsigned k = 2; k <= P2; k <<= 1) {
            for (unsigned j = k >> 1; j > 0; j >>= 1) {
                for (unsigned t2 = t; t2 < P2 / 2; t2 += 256) {
                    unsigned i = ((t2 & ~(j - 1)) << 1) | (t2 & (j - 1));
                    unsigned p2i = i + j;
                    bool dir = ((i & k) == 0);
                    unsigned long long a = sel[i], c = sel[p2i];
                    if ((a < c) == dir) { sel[i] = c; sel[p2i] = a; }
                }
                __syncthreads();
            }
        }
        // decode boxes for selected
        for (unsigned i = t; i < S; i += 256) {
            unsigned long long kk = sel[i];
            float4 bx = {0.f, 0.f, 0.f, 0.f};
            if (kk) {
                unsigned flat = ~(unsigned)kk;
                unsigned a = flat / CC;
                float px = points[a * 2 + 0], py = points[a * 2 + 1];
                const float* rg = regress + ((size_t)b * NN + a) * 4;
                bx.x = fminf(fmaxf(px - rg[0], 0.f), 1.f);
                bx.y = fminf(fmaxf(py - rg[1], 0.f), 1.f);
                bx.z = fminf(fmaxf(px + rg[2], 0.f), 1.f);
                bx.w = fminf(fmaxf(py + rg[3], 0.f), 1.f);
            }
            sbox[i] = bx;
        }
        __syncthreads();
        // single-wave scan, kept boxes cached in registers (lane owns slots lane, lane+64)
        if (t < 64) {
            int lane = t;
            float4 kb0 = {0, 0, 0, 0}, kb1 = {0, 0, 0, 0};
            unsigned kc0 = 0xFFFFFFFFu, kc1 = 0xFFFFFFFFu;
            int cnt = 0;
            for (unsigned i = 0; i < S && cnt < PROP; i++) {
                unsigned long long kk = sel[i];
                if (!kk) break;
                unsigned flat = ~(unsigned)kk;
                unsigned a = flat / CC;
                unsigned ccls = flat - a * CC;
                float4 c4 = sbox[i];
                float ca = (c4.z - c4.x) * (c4.w - c4.y);
                bool sup = false;
                if (lane < cnt && kc0 == ccls) {
                    float w = fmaxf(fminf(c4.z, kb0.z) - fmaxf(c4.x, kb0.x), 0.f);
                    float h = fmaxf(fminf(c4.w, kb0.w) - fmaxf(c4.y, kb0.y), 0.f);
                    float inter = w * h;
                    float ka = (kb0.z - kb0.x) * (kb0.w - kb0.y);
                    sup = inter / fmaxf(ca + ka - inter, 1e-9f) > 0.5f;
                }
                if (lane + 64 < cnt && kc1 == ccls) {
                    float w = fmaxf(fminf(c4.z, kb1.z) - fmaxf(c4.x, kb1.x), 0.f);
                    float h = fmaxf(fminf(c4.w, kb1.w) - fmaxf(c4.y, kb1.y), 0.f);
                    float inter = w * h;
                    float ka = (kb1.z - kb1.x) * (kb1.w - kb1.y);
                    sup = sup || (inter / fmaxf(ca + ka - inter, 1e-9f) > 0.5f);
                }
                if (!__any(sup)) {
                    if (lane == cnt) { kb0 = c4; kc0 = ccls; }
                    if (lane == cnt - 64) { kb1 = c4; kc1 = ccls; }
                    if (lane == 0) { kbox[cnt] = c4; selAnc[cnt] = a; }
                    cnt++;
                }
            }
            if (lane == 0) sc[3] = (unsigned)cnt;
        }
        __syncthreads();
        if (t == 0) sc[4] = (sc[3] < PROP && sc[1] < sc[0]) ? 1u : 0u;
        __syncthreads();
        if (!sc[4]) break;   // uniform condition
    }

    // outputs: out_logit [B][PROP][CC] then out_box [B][PROP][4]
    unsigned nk = sc[3];
    float* outL = out + (size_t)b * PROP * CC;
    const float* lgb = logits + (size_t)b * NC;
    const float* cb = cent + (size_t)b * NN;
    for (int s = t; s < PROP * CC; s += 256) {
        int p = s / CC;
        int c = s - p * CC;
        float v = 0.f;
        if ((unsigned)p < nk) {
            unsigned a = selAnc[p];
            v = sqrtf(lgb[(size_t)a * CC + c] * cb[a]);
        }
        outL[s] = v;
    }
    float* outB = out + (size_t)BB * PROP * CC + (size_t)b * PROP * 4;
    for (int s = t; s < PROP * 4; s += 256) {
        int p = s >> 2;
        float v = 0.f;
        if ((unsigned)p < nk) v = ((const float*)&kbox[p])[s & 3];
        outB[s] = v;
    }
}

extern "C" void kernel_launch(void* const* d_in, const int* in_sizes, int n_in,
                              void* d_out, int out_size, void* d_ws, size_t ws_size,
                              hipStream_t stream) {
    const float* logits  = (const float*)d_in[0];
    const float* regress = (const float*)d_in[1];
    const float* points  = (const float*)d_in[2];
    const float* cent    = (const float*)d_in[3];
    float* out = (float*)d_out;

    char* ws = (char*)d_ws;
    unsigned* hist = (unsigned*)ws;
    unsigned* ctrl = (unsigned*)(ws + CTRL_OFF);
    unsigned long long* candA = (unsigned long long*)(ws + CANDA_OFF);
    unsigned long long* candB = (unsigned long long*)(ws + CANDB_OFF);
    unsigned long long* spill = (unsigned long long*)(ws + SPILL_OFF);

    hipMemsetAsync(d_ws, 0, ZERO_BYTES, stream);
    if (ws_size >= WS_NEEDED) {
        k_pass1<<<dim3(512, BB), 256, 0, stream>>>(logits, cent, ctrl, spill);
        k_slowflag<<<1, 64, 0, stream>>>(ctrl);
        k_hist_spill<<<dim3(32, BB), 256, 0, stream>>>(ctrl, spill, hist);
        k_hist<<<dim3(256, BB), 256, 0, stream>>>(logits, cent, hist, ctrl);        // guarded slow path
        k_select<<<BB, 256, 0, stream>>>(hist, ctrl);
        k_compact_fast<<<dim3(32, BB), 256, 0, stream>>>(ctrl, spill, candA, candB);
        k_compact<<<dim3(256, BB), 256, 0, stream>>>(logits, cent, ctrl, candA, candB);  // guarded slow path
    } else {
        hipMemsetAsync(ws + CTRL_OFF + 28, 1, 1, stream);  // force validated full-scan path
        k_hist<<<dim3(256, BB), 256, 0, stream>>>(logits, cent, hist, ctrl);
        k_select<<<BB, 256, 0, stream>>>(hist, ctrl);
        k_compact<<<dim3(256, BB), 256, 0, stream>>>(logits, cent, ctrl, candA, candB);
    }
    k_boundary<<<BB, 256, 0, stream>>>(ctrl, candA, candB);
    k_nms<<<BB, 256, 0, stream>>>(logits, regress, points, cent, candA, out);
}